// Round 9
// baseline (482.468 us; speedup 1.0000x reference)
//
#include <hip/hip_runtime.h>
#include <math.h>

// ---------------------------------------------------------------------------
// BertLayer forward on gfx950. Round 19: Wo -> gemm256 split-K (race-free) +
// batched weight transposes.
// Established: inputs fp32, output fp32, bf16-emulated ref (thr 0.10625).
// vs r18 (PASS 481us; FF on gemm256 86.4 vs 96.9 on gemm128d -- hybrid good,
// total delta vs r16 = container noise):
//   Wo was on gemm128d (97us) only because unsplit gemm256 under-fills (128
//   blocks) and r15's split-K raced (ff/z2b ws overlap). r19: split-K=2 on
//   gemm256 with BF16 partials z2a@ws+9MB (over WiT, dead after FF) and
//   z2b@ws+25MB (over xb, dead after Wd) -- zero overlap by construction;
//   grid (128,2)=256 blocks = exact 1/CU fill. LN2 IN_MODE=3 (bf16+bf16).
//   bf16-partial rounding ~0.002 absmax vs 0.106 thr. Also: 4x ExE weight
//   transposes batched into one z=4 launch (WqT..WdT contiguous).
// ---------------------------------------------------------------------------

typedef __bf16 bf16;
typedef __attribute__((ext_vector_type(8))) __bf16 bf16x8;
typedef __attribute__((ext_vector_type(4))) __bf16 bf16x4;
typedef __attribute__((ext_vector_type(4))) float f32x4;

#define BM 128
#define BN 128
#define BK 64
#define SCS 140   // epilogue LDS row stride (floats) for old kernel

__device__ __forceinline__ void async_cp16(const bf16* g, bf16* l) {
    __builtin_amdgcn_global_load_lds((__attribute__((address_space(1))) void*)(g),
                                     (__attribute__((address_space(3))) void*)(l),
                                     16, 0, 0);
}

// gelu(x) ~= x * sigmoid(1.59577*x*(1+0.044715*x^2)); max abs err ~3e-3.
__device__ __forceinline__ float gelu_fast(float x) {
    float u = x * x;
    float y = 1.5957691216f * x * fmaf(0.044715f, u, 1.0f);
    float e = __expf(-y);
    return x * __builtin_amdgcn_rcpf(1.0f + e);
}

__device__ __forceinline__ float load_dual(const void* p, long long i, int f32) {
    return f32 ? ((const float*)p)[i] : (float)((const bf16*)p)[i];
}

// --- dtype detect / sentinel ------------------------------------------------

__global__ void diag_init(const void* x, int* dflag)
{
    const int t = threadIdx.x;            // 0..63
    const bf16* xb = (const bf16*)x;
    float a = (float)xb[2 * t];
    float b = (float)xb[2 * t + 1];
    auto wild = [](float v) -> bool {
        float af = fabsf(v);
        return !(af <= 3.0e38f) || af > 1.0e3f || (v != 0.0f && af < 1.0e-8f);
    };
    unsigned long long ba = __ballot(wild(a));
    unsigned long long bb = __ballot(wild(b));
    if (t == 0) *dflag = (__popcll(ba) + __popcll(bb) > 16) ? 1 : 0;
}

__global__ void sentinel_small(float* out) { out[0] = 2048.0f; }

// --- input normalization ----------------------------------------------------

__global__ __launch_bounds__(256)
void convert_vec4(const void* src, bf16* dst, long long n4, const int* dflag)
{
    const int f32 = *dflag;
    long long i = (long long)blockIdx.x * 256 + threadIdx.x;
    if (i >= n4) return;
    bf16x4 o;
    if (f32) {
        f32x4 v = ((const f32x4*)src)[i];
        #pragma unroll
        for (int j = 0; j < 4; j++) o[j] = (bf16)v[j];
    } else {
        o = ((const bf16x4*)src)[i];
    }
    ((bf16x4*)dst)[i] = o;
}

struct SmallPtrs { const void* p[10]; };   // 9x E vectors + 1x F vector

__global__ __launch_bounds__(256)
void convert_small(SmallPtrs sp, bf16* dst, const int* dflag)
{
    const int f32 = *dflag;
    const int idx = blockIdx.x * 256 + threadIdx.x;   // 0..13311
    if (idx >= 13312) return;
    const int seg = idx >> 10;
    float v;
    if (seg < 9) v = load_dual(sp.p[seg], idx & 1023, f32);
    else         v = load_dual(sp.p[9], idx - 9216, f32);
    dst[idx] = (bf16)v;
}

__global__ __launch_bounds__(256)
void transpose_dual(const void* in, bf16* out, int R, int C, const int* dflag)
{
    __shared__ bf16 tile[32][33];
    const int f32 = *dflag;
    const int c0 = blockIdx.x * 32, r0 = blockIdx.y * 32;
    const int tx = threadIdx.x, ty = threadIdx.y;
    #pragma unroll
    for (int i = 0; i < 32; i += 8)
        tile[ty + i][tx] = (bf16)load_dual(in, (long long)(r0 + ty + i) * C + (c0 + tx), f32);
    __syncthreads();
    #pragma unroll
    for (int i = 0; i < 32; i += 8)
        out[(long long)(c0 + ty + i) * R + (r0 + tx)] = tile[tx][ty + i];
}

struct W4Ptrs { const void* p[4]; };

// 4 same-shape square transposes in one launch (z selects matrix).
__global__ __launch_bounds__(256)
void transpose_quad(W4Ptrs wp, bf16* outbase, int R, int C, const int* dflag)
{
    __shared__ bf16 tile[32][33];
    const int f32 = *dflag;
    const void* in = wp.p[blockIdx.z];
    bf16* out = outbase + (long long)blockIdx.z * (long long)R * C;
    const int c0 = blockIdx.x * 32, r0 = blockIdx.y * 32;
    const int tx = threadIdx.x, ty = threadIdx.y;
    #pragma unroll
    for (int i = 0; i < 32; i += 8)
        tile[ty + i][tx] = (bf16)load_dual(in, (long long)(r0 + ty + i) * C + (c0 + tx), f32);
    __syncthreads();
    #pragma unroll
    for (int i = 0; i < 32; i += 8)
        out[(long long)(c0 + ty + i) * R + (r0 + tx)] = tile[tx][ty + i];
}

__global__ __launch_bounds__(256)
void transpose_b(const bf16* __restrict__ in, bf16* __restrict__ out, int R, int C)
{
    __shared__ bf16 tile[32][33];
    const long long z = (long long)blockIdx.z * (long long)R * C;
    const int c0 = blockIdx.x * 32, r0 = blockIdx.y * 32;
    const int tx = threadIdx.x, ty = threadIdx.y;
    #pragma unroll
    for (int i = 0; i < 32; i += 8)
        tile[ty + i][tx] = in[z + (long long)(r0 + ty + i) * C + (c0 + tx)];
    __syncthreads();
    #pragma unroll
    for (int i = 0; i < 32; i += 8)
        out[z + (long long)(c0 + ty + i) * R + (r0 + tx)] = tile[tx][ty + i];
}

// --- GEMM 128^2: producer-consumer (fallback path only) ---------------------
template<int ACT, int HAS_BIAS, int HAS_RES, int OUT_F32>
__global__ __launch_bounds__(512)
void gemm_bt(const bf16* __restrict__ A, const bf16* __restrict__ Bt,
             const bf16* __restrict__ bias, const bf16* __restrict__ res,
             void* __restrict__ Cout, int M, int N, int K, float scale,
             long long bsA, long long bsB, long long bsC, long long bsBias)
{
    __shared__ __align__(16) char smem[65536];   // 2 x (sA 16KB + sB 16KB)
    float* sC = (float*)smem;                    // epilogue [64][SCS]

    const int tid  = threadIdx.x;
    const int lane = tid & 63;
    const int wave = tid >> 6;          // 0..7
    const int pw   = wave & 3;
    const int wm   = pw >> 1;
    const int wn   = pw & 1;
    const bool producer = (wave >= 4);
    const int m0   = blockIdx.y * BM;
    const int n0   = blockIdx.x * BN;
    const long long zA = (long long)blockIdx.z * bsA;
    const long long zB = (long long)blockIdx.z * bsB;
    const long long zC = (long long)blockIdx.z * bsC;
    const bf16* biasz = HAS_BIAS ? (bias + (long long)blockIdx.z * bsBias) : nullptr;
    const int nIter = K >> 6;

    f32x4 acc[4][4];
    const bf16* gA[4]; const bf16* gB[4]; int lo[4];

    if (producer) {
        #pragma unroll
        for (int j = 0; j < 4; j++) {
            const int ci  = j * 256 + pw * 64 + lane;
            const int row = ci >> 3;
            const int c8  = ((ci & 7) ^ (row & 7)) * 8;   // swizzle
            gA[j] = A + zA + (long long)(m0 + row) * K + c8;
            gB[j] = Bt + zB + (long long)(n0 + row) * K + c8;
            lo[j] = (j * 256 + pw * 64) * 8;              // element offset
        }
        bf16* dA = (bf16*)smem;
        bf16* dB = (bf16*)(smem + 16384);
        #pragma unroll
        for (int j = 0; j < 4; j++) {
            async_cp16(gA[j], dA + lo[j]);
            async_cp16(gB[j], dB + lo[j]);
            gA[j] += BK; gB[j] += BK;
        }
    } else {
        const f32x4 zf = {0.f, 0.f, 0.f, 0.f};
        #pragma unroll
        for (int i = 0; i < 4; i++)
            #pragma unroll
            for (int j = 0; j < 4; j++) acc[i][j] = zf;
    }
    __syncthreads();

    const int fr   = lane & 15;
    const int x0   = (lane >> 4) ^ (fr & 7);
    const int arow = wm * 64 + fr;
    const int brow = wn * 64 + fr;

    for (int kt = 0; kt < nIter; ++kt) {
        if (producer) {
            if (kt + 1 < nIter) {
                const int bo = ((kt + 1) & 1) ? 32768 : 0;
                bf16* dA = (bf16*)(smem + bo);
                bf16* dB = (bf16*)(smem + bo + 16384);
                #pragma unroll
                for (int j = 0; j < 4; j++) {
                    async_cp16(gA[j], dA + lo[j]);
                    async_cp16(gB[j], dB + lo[j]);
                    gA[j] += BK; gB[j] += BK;
                }
            }
        } else {
            const int bo = (kt & 1) ? 32768 : 0;
            const bf16* sAk = (const bf16*)(smem + bo);
            const bf16* sBk = (const bf16*)(smem + bo + 16384);
            #pragma unroll
            for (int s = 0; s < 2; s++) {
                const int xo = (x0 ^ (s << 2)) * 8;
                bf16x8 afr[4], bfr[4];
                #pragma unroll
                for (int mi = 0; mi < 4; mi++) afr[mi] = *(const bf16x8*)(sAk + (arow + mi * 16) * 64 + xo);
                #pragma unroll
                for (int ni = 0; ni < 4; ni++) bfr[ni] = *(const bf16x8*)(sBk + (brow + ni * 16) * 64 + xo);
                #pragma unroll
                for (int mi = 0; mi < 4; mi++)
                    #pragma unroll
                    for (int ni = 0; ni < 4; ni++)
                        acc[mi][ni] = __builtin_amdgcn_mfma_f32_16x16x32_bf16(afr[mi], bfr[ni], acc[mi][ni], 0, 0, 0);
            }
        }
        __syncthreads();
    }

    const int q4 = lane >> 4;
    for (int h = 0; h < 2; h++) {
        __syncthreads();
        if (!producer && wm == h) {
            #pragma unroll
            for (int mi = 0; mi < 4; mi++)
                #pragma unroll
                for (int r = 0; r < 4; r++) {
                    const int lr = mi * 16 + q4 * 4 + r;
                    #pragma unroll
                    for (int ni = 0; ni < 4; ni++)
                        sC[lr * SCS + wn * 64 + ni * 16 + fr] = acc[mi][ni][r];
                }
        }
        __syncthreads();
        const int lr = tid >> 3;             // 0..63
        const int cb = (tid & 7) * 16;       // 0..112
        const long long grow  = m0 + h * 64 + lr;
        const long long gbase = zC + grow * (long long)N + (n0 + cb);
        const float* srow = sC + lr * SCS + cb;
        #pragma unroll
        for (int g = 0; g < 2; g++) {
            f32x4 v0 = *(const f32x4*)(srow + g * 8);
            f32x4 v1 = *(const f32x4*)(srow + g * 8 + 4);
            float vv[8] = {v0[0], v0[1], v0[2], v0[3], v1[0], v1[1], v1[2], v1[3]};
            if constexpr (HAS_BIAS) {
                bf16x8 bb = *(const bf16x8*)(biasz + n0 + cb + g * 8);
                #pragma unroll
                for (int j = 0; j < 8; j++) vv[j] = vv[j] * scale + (float)bb[j];
            } else {
                #pragma unroll
                for (int j = 0; j < 8; j++) vv[j] *= scale;
            }
            if constexpr (ACT == 1) {
                #pragma unroll
                for (int j = 0; j < 8; j++) vv[j] = gelu_fast(vv[j]);
            }
            if constexpr (HAS_RES) {
                bf16x8 rr = *(const bf16x8*)(res + gbase + g * 8);
                #pragma unroll
                for (int j = 0; j < 8; j++) vv[j] += (float)rr[j];
            }
            if constexpr (OUT_F32) {
                f32x4 o0 = {vv[0], vv[1], vv[2], vv[3]};
                f32x4 o1 = {vv[4], vv[5], vv[6], vv[7]};
                *(f32x4*)((float*)Cout + gbase + g * 8)     = o0;
                *(f32x4*)((float*)Cout + gbase + g * 8 + 4) = o1;
            } else {
                bf16x8 o;
                #pragma unroll
                for (int j = 0; j < 8; j++) o[j] = (bf16)vv[j];
                *(bf16x8*)((bf16*)Cout + gbase + g * 8) = o;
            }
        }
    }
}

// --- GEMM 256x256, 8-phase, row-half staging + quadrant phases (r14) --------
// Measured best for the big GEMMs (FF 86.4us vs 96.9 on gemm128d). 1 blk/CU.
template<int ACT, int HAS_BIAS, int HAS_RES, int OUT_F32, int SPLITK>
__global__ __launch_bounds__(512, 2)
void gemm256(const bf16* __restrict__ A, const bf16* __restrict__ Bt,
             const bf16* __restrict__ bias, const bf16* __restrict__ res,
             void* __restrict__ Cout, void* __restrict__ Cout2,
             int M, int N, int K, int ldk, float scale,
             long long bsB, long long bsC, long long bsBias)
{
    __shared__ __align__(16) char smem[131072];

    const int tid  = threadIdx.x;
    const int lane = tid & 63;
    const int wave = tid >> 6;          // 0..7
    const int wm   = wave >> 2;         // 0..1
    const int wn   = wave & 3;          // 0..3

    // bijective XCD swizzle on flat workgroup id (m204 variant)
    const int gx  = N >> 8;
    const int nwg = gx * (M >> 8);
    int wg = blockIdx.x;
    {
        const int q = nwg >> 3, r = nwg & 7;
        const int xcd = wg & 7, lid = wg >> 3;
        wg = (xcd < r ? xcd * (q + 1) : r * (q + 1) + (xcd - r) * q) + lid;
    }
    const int bx = wg % gx, by = wg / gx;
    const int m0 = by << 8, n0 = bx << 8;
    const int zi = blockIdx.y;          // batch (SPLITK=0) or k-chunk (=1)

    const bf16* Ab = A  + (SPLITK ? (long long)zi * K : 0);
    const bf16* Bb = Bt + (SPLITK ? (long long)zi * K : (long long)zi * bsB);
    const bool  bon = HAS_BIAS && (!SPLITK || zi == 0);
    const bool  ron = HAS_RES  && (!SPLITK || zi == 0);
    const bf16* biasz = HAS_BIAS ? (bias + (SPLITK ? 0 : (long long)zi * bsBias)) : nullptr;
    const long long coff = SPLITK ? 0 : (long long)zi * bsC;
    char* const Cb = (char*)((SPLITK && zi) ? Cout2 : Cout);

    // DMA source addressing (inverse of LDS granule permutation)
    const int rg0 = wave * 16 + (lane >> 3);       // row within half [0,128)
    const int cg0 = (lane & 7) ^ (lane >> 3);      // granule column 0..7
    const bf16* aSrc[2]; const bf16* bSrc[2];
    #pragma unroll
    for (int h = 0; h < 2; h++) {
        aSrc[h] = Ab + (long long)(m0 + h * 128 + rg0) * ldk + cg0 * 8;
        bSrc[h] = Bb + (long long)(n0 + h * 128 + rg0) * ldk + cg0 * 8;
    }
    const int sq8 = 8 * ldk;                       // qq=1: row+8, same c

    // ds_read byte addresses: aAddr/bAddr[buf*2+kk]
    const int fr = lane & 15, chk = lane >> 4;
    unsigned aAddr[4], bAddr[4];
    {
        const unsigned sm3 = (unsigned)(size_t)(__attribute__((address_space(3))) char*)smem;
        #pragma unroll
        for (int cb = 0; cb < 2; cb++)
            #pragma unroll
            for (int kk = 0; kk < 2; kk++) {
                const unsigned slot = (unsigned)(((kk * 4 + chk) ^ (fr & 7)) * 16);
                aAddr[cb * 2 + kk] = sm3 + cb * 65536 + wm * 16384
                                   + fr * 128 + slot;
                bAddr[cb * 2 + kk] = sm3 + cb * 65536 + 32768 + (wn >> 1) * 16384
                                   + ((wn & 1) * 64 + fr) * 128 + slot;
            }
    }

#define DSR(d, b, imm) \
    asm volatile("ds_read_b128 %0, %1 offset:%c2" : "=v"(d) : "v"(b), "i"(imm))
// A quadrant q reads: set[0]=(i0,kk0) set[1]=(i0,kk1) set[2]=(i1,kk0) set[3]=(i1,kk1)
#define RDA4(set, cb, q) do { \
    DSR(set[0], aAddr[(cb) * 2 + 0], (q) * 4096); \
    DSR(set[1], aAddr[(cb) * 2 + 1], (q) * 4096); \
    DSR(set[2], aAddr[(cb) * 2 + 0], (q) * 4096 + 2048); \
    DSR(set[3], aAddr[(cb) * 2 + 1], (q) * 4096 + 2048); \
} while (0)
// B all 4 n-frags x kk: bv[j*2+kk]
#define RDB8(cb) do { \
    DSR(bv[0], bAddr[(cb) * 2 + 0], 0);    DSR(bv[1], bAddr[(cb) * 2 + 1], 0); \
    DSR(bv[2], bAddr[(cb) * 2 + 0], 2048); DSR(bv[3], bAddr[(cb) * 2 + 1], 2048); \
    DSR(bv[4], bAddr[(cb) * 2 + 0], 4096); DSR(bv[5], bAddr[(cb) * 2 + 1], 4096); \
    DSR(bv[6], bAddr[(cb) * 2 + 0], 6144); DSR(bv[7], bAddr[(cb) * 2 + 1], 6144); \
} while (0)
#define STG(buf, mat, h, t) do { \
    bf16* _d = (bf16*)(smem + (buf) * 65536 + (mat) * 32768 + (h) * 16384 + wave * 2048); \
    const bf16* _s = ((mat) ? bSrc[h] : aSrc[h]) + (t) * 64; \
    async_cp16(_s, _d); \
    async_cp16(_s + sq8, _d + 512); \
} while (0)
#define IF_STG(c, buf, mat, h, t) do { if (c) STG(buf, mat, h, t); } while (0)
#define BARR __builtin_amdgcn_s_barrier()
#define SB0  __builtin_amdgcn_sched_barrier(0)
#define LGKM0 asm volatile("s_waitcnt lgkmcnt(0)")
#define VM_WAIT(c) do { \
    if (c) asm volatile("s_waitcnt vmcnt(4)"); \
    else   asm volatile("s_waitcnt vmcnt(0)"); \
} while (0)
// 16 MFMA: kk0 (8 indep), then kk1 (8, each dep on its kk0 partner)
#define MMA(q, ASET) do { \
    __builtin_amdgcn_s_setprio(1); \
    _Pragma("unroll") \
    for (int _j = 0; _j < 4; _j++) { \
        acc[(q) * 2 + 0][_j] = __builtin_amdgcn_mfma_f32_16x16x32_bf16(ASET[0], bv[_j * 2 + 0], acc[(q) * 2 + 0][_j], 0, 0, 0); \
        acc[(q) * 2 + 1][_j] = __builtin_amdgcn_mfma_f32_16x16x32_bf16(ASET[2], bv[_j * 2 + 0], acc[(q) * 2 + 1][_j], 0, 0, 0); \
    } \
    _Pragma("unroll") \
    for (int _j = 0; _j < 4; _j++) { \
        acc[(q) * 2 + 0][_j] = __builtin_amdgcn_mfma_f32_16x16x32_bf16(ASET[1], bv[_j * 2 + 1], acc[(q) * 2 + 0][_j], 0, 0, 0); \
        acc[(q) * 2 + 1][_j] = __builtin_amdgcn_mfma_f32_16x16x32_bf16(ASET[3], bv[_j * 2 + 1], acc[(q) * 2 + 1][_j], 0, 0, 0); \
    } \
    __builtin_amdgcn_s_setprio(0); \
} while (0)

    const int NT = K >> 6, NI = NT >> 1;

    // prologue: tile0 A+B (buf0) + tile1 B (buf1); A(t1) staged at e-q0/q1
    STG(0, 0, 0, 0); STG(0, 0, 1, 0); STG(0, 1, 0, 0); STG(0, 1, 1, 0);
    STG(1, 1, 0, 1); STG(1, 1, 1, 1);

    f32x4 acc[8][4];
    {
        const f32x4 zf = {0.f, 0.f, 0.f, 0.f};
        #pragma unroll
        for (int i = 0; i < 8; i++)
            #pragma unroll
            for (int j = 0; j < 4; j++) acc[i][j] = zf;
    }
    bf16x8 avA[4], avB[4], bv[8];

    asm volatile("s_waitcnt vmcnt(4)");   // drain tile0, allow B(t1) in flight
    BARR;

    for (int it = 0; it < NI; ++it) {
        const int o = 2 * it + 1, e2 = 2 * it + 2, o2 = 2 * it + 3;
        const bool se = e2 < NT, so = o2 < NT;
        // ===== tile e = 2*it in buf0 =====
        // q0: serial B(8)+A(4); stage A-h0(o)
        RDB8(0);
        RDA4(avA, 0, 0);
        STG(1, 0, 0, o);
        BARR; LGKM0; SB0;
        RDA4(avB, 0, 1); SB0;
        MMA(0, avA);
        BARR;
        // q1: stage A-h1(o)
        STG(1, 0, 1, o);
        BARR; LGKM0; SB0;
        RDA4(avA, 0, 2); SB0;
        MMA(1, avB);
        BARR;
        // q2: stage B-h0(e2)
        IF_STG(se, 0, 1, 0, e2);
        BARR; LGKM0; SB0;
        RDA4(avB, 0, 3); SB0;
        MMA(2, avA);
        BARR;
        // q3: stage B-h1(e2); edge
        IF_STG(se, 0, 1, 1, e2);
        BARR; LGKM0; SB0;
        MMA(3, avB); SB0;
        VM_WAIT(se);
        BARR;
        // ===== tile o = 2*it+1 in buf1 =====
        // q0: serial B(8)+A(4); stage A-h0(e2)
        RDB8(1);
        RDA4(avA, 1, 0);
        IF_STG(se, 0, 0, 0, e2);
        BARR; LGKM0; SB0;
        RDA4(avB, 1, 1); SB0;
        MMA(0, avA);
        BARR;
        // q1: stage A-h1(e2)
        IF_STG(se, 0, 0, 1, e2);
        BARR; LGKM0; SB0;
        RDA4(avA, 1, 2); SB0;
        MMA(1, avB);
        BARR;
        // q2: stage B-h0(o2)
        IF_STG(so, 1, 1, 0, o2);
        BARR; LGKM0; SB0;
        RDA4(avB, 1, 3); SB0;
        MMA(2, avA);
        BARR;
        // q3: stage B-h1(o2); edge
        IF_STG(so, 1, 1, 1, o2);
        BARR; LGKM0; SB0;
        MMA(3, avB); SB0;
        VM_WAIT(so);
        BARR;
    }
#undef MMA
#undef VM_WAIT
#undef LGKM0
#undef SB0
#undef BARR
#undef IF_STG
#undef STG
#undef RDB8
#undef RDA4
#undef DSR

    // epilogue: 4 passes of 64 rows through LDS (reuses the 128KB buffer)
    float* sC = (float*)smem;
    const int q4 = lane >> 4;
    const int lr = tid >> 3;            // 0..63
    const int c0 = (tid & 7) * 4;       // scattered 16B chunks
    const long long Nll = N;
    #pragma unroll
    for (int p = 0; p < 4; p++) {
        __syncthreads();
        if (wm == (p >> 1)) {
            #pragma unroll
            for (int i = 0; i < 4; i++) {
                const int fi = (p & 1) * 4 + i;
                #pragma unroll
                for (int r = 0; r < 4; r++) {
                    const int row = i * 16 + q4 * 4 + r;
                    #pragma unroll
                    for (int j = 0; j < 4; j++)
                        sC[row * 260 + wn * 64 + j * 16 + fr] = acc[fi][j][r];
                }
            }
        }
        __syncthreads();
        const long long grow = m0 + p * 64 + lr;
        const long long gb = grow * Nll + n0;
        const float* srow = sC + lr * 260;
        #pragma unroll
        for (int g = 0; g < 8; g++) {
            const int col = c0 + g * 32;
            f32x4 v = *(const f32x4*)(srow + col);
            float vv[4] = {v[0], v[1], v[2], v[3]};
            if (bon) {
                bf16x4 bb = *(const bf16x4*)(biasz + n0 + col);
                #pragma unroll
                for (int j = 0; j < 4; j++) vv[j] = vv[j] * scale + (float)bb[j];
            } else {
                #pragma unroll
                for (int j = 0; j < 4; j++) vv[j] *= scale;
            }
            if constexpr (ACT == 1) {
                #pragma unroll
                for (int j = 0; j < 4; j++) vv[j] = gelu_fast(vv[j]);
            }
            if (ron) {
                bf16x4 rr = *(const bf16x4*)(res + gb + col);
                #pragma unroll
                for (int j = 0; j < 4; j++) vv[j] += (float)rr[j];
            }
            if constexpr (OUT_F32) {
                f32x4 o4 = {vv[0], vv[1], vv[2], vv[3]};
                *(f32x4*)((float*)Cb + coff + gb + col) = o4;
            } else {
                bf16x4 o4;
                #pragma unroll
                for (int j = 0; j < 4; j++) o4[j] = (bf16)vv[j];
                *(bf16x4*)((bf16*)Cb + coff + gb + col) = o4;
            }
        }
    }
}

// --- GEMM 128x128 double-buffered, 2 blocks/CU (r16 verbatim) ---------------
// Measured best for scores/PV/Wd.
template<int ACT, int HAS_BIAS, int HAS_RES, int OUT_F32, int SPLITK>
__global__ __launch_bounds__(512, 4)
void gemm128d(const bf16* __restrict__ A, const bf16* __restrict__ Bt,
              const bf16* __restrict__ bias, const bf16* __restrict__ res,
              void* __restrict__ Cout, void* __restrict__ Cout2,
              int M, int N, int K, int ldk, float scale,
              long long bsA, long long bsB, long long bsC, long long bsBias)
{
    __shared__ __align__(16) char smem[65536];

    const int tid  = threadIdx.x;
    const int lane = tid & 63;
    const int wave = tid >> 6;          // 0..7
    const int wm   = wave >> 2;         // 0..1  (m half: 64 rows)
    const int wn   = wave & 3;          // 0..3  (n quarter: 32 cols)

    // bijective XCD swizzle on flat workgroup id (m204 variant)
    const int gx  = N >> 7;
    const int nwg = gx * (M >> 7);
    int wg = blockIdx.x;
    {
        const int q = nwg >> 3, r = nwg & 7;
        const int xcd = wg & 7, lid = wg >> 3;
        wg = (xcd < r ? xcd * (q + 1) : r * (q + 1) + (xcd - r) * q) + lid;
    }
    const int bx = wg % gx, by = wg / gx;
    const int m0 = by << 7, n0 = bx << 7;
    const int zi = blockIdx.y;          // batch (SPLITK=0) or k-chunk (=1)

    const bf16* Ab = A  + (SPLITK ? (long long)zi * K : (long long)zi * bsA);
    const bf16* Bb = Bt + (SPLITK ? (long long)zi * K : (long long)zi * bsB);
    const bool  bon = HAS_BIAS && (!SPLITK || zi == 0);
    const bool  ron = HAS_RES  && (!SPLITK || zi == 0);
    const bf16* biasz = HAS_BIAS ? (bias + (SPLITK ? 0 : (long long)zi * bsBias)) : nullptr;
    const long long coff = SPLITK ? 0 : (long long)zi * bsC;
    char* const Cb = (char*)((SPLITK && zi) ? Cout2 : Cout);

    // DMA sources: rows rg0, rg0+8 of the 128-row tile, granule col cg0
    // (inverse of LDS granule permutation; full 128B lines per row).
    const int rg0 = wave * 16 + (lane >> 3);
    const int cg0 = (lane & 7) ^ (lane >> 3);
    const bf16* aSrc = Ab + (long long)(m0 + rg0) * ldk + cg0 * 8;
    const bf16* bSrc = Bb + (long long)(n0 + rg0) * ldk + cg0 * 8;
    const int sq8 = 8 * ldk;

    // ds_read base addrs [buf][kk]; frag offsets via imm (mi|ni * 2048).
    const int fr = lane & 15, chk = lane >> 4;
    unsigned aAd[2][2], bAd[2][2];
    {
        const unsigned sm3 = (unsigned)(size_t)(__attribute__((address_space(3))) char*)smem;
        #pragma unroll
        for (int p = 0; p < 2; p++)
            #pragma unroll
            for (int kk = 0; kk < 2; kk++) {
                const unsigned slot = (unsigned)(((kk * 4 + chk) ^ (fr & 7)) * 16);
                aAd[p][kk] = sm3 + p * 32768 + (wm * 64 + fr) * 128 + slot;
                bAd[p][kk] = sm3 + p * 32768 + 16384 + (wn * 32 + fr) * 128 + slot;
            }
    }

#define DSR(d, b, imm) \
    asm volatile("ds_read_b128 %0, %1 offset:%c2" : "=v"(d) : "v"(b), "i"(imm))
#define MM8(mh) do { \
    _Pragma("unroll") \
    for (int _n = 0; _n < 2; _n++) { \
        acc[(mh) * 2 + 0][_n] = __builtin_amdgcn_mfma_f32_16x16x32_bf16(av[((mh) * 2 + 0) * 2 + 0], bv[_n * 2 + 0], acc[(mh) * 2 + 0][_n], 0, 0, 0); \
        acc[(mh) * 2 + 1][_n] = __builtin_amdgcn_mfma_f32_16x16x32_bf16(av[((mh) * 2 + 1) * 2 + 0], bv[_n * 2 + 0], acc[(mh) * 2 + 1][_n], 0, 0, 0); \
    } \
    _Pragma("unroll") \
    for (int _n = 0; _n < 2; _n++) { \
        acc[(mh) * 2 + 0][_n] = __builtin_amdgcn_mfma_f32_16x16x32_bf16(av[((mh) * 2 + 0) * 2 + 1], bv[_n * 2 + 1], acc[(mh) * 2 + 0][_n], 0, 0, 0); \
        acc[(mh) * 2 + 1][_n] = __builtin_amdgcn_mfma_f32_16x16x32_bf16(av[((mh) * 2 + 1) * 2 + 1], bv[_n * 2 + 1], acc[(mh) * 2 + 1][_n], 0, 0, 0); \
    } \
} while (0)
// One K-tile from buf p; stage next tile into buf p^1 when SC.
#define TILE(p, SC) do { \
    DSR(bv[0], bAd[p][0], 0);    DSR(bv[1], bAd[p][1], 0); \
    DSR(bv[2], bAd[p][0], 2048); DSR(bv[3], bAd[p][1], 2048); \
    DSR(av[0], aAd[p][0], 0);    DSR(av[1], aAd[p][1], 0); \
    DSR(av[2], aAd[p][0], 2048); DSR(av[3], aAd[p][1], 2048); \
    DSR(av[4], aAd[p][0], 4096); DSR(av[5], aAd[p][1], 4096); \
    DSR(av[6], aAd[p][0], 6144); DSR(av[7], aAd[p][1], 6144); \
    if (SC) { \
        bf16* _dA = (bf16*)(smem + ((p) ^ 1) * 32768 + wave * 2048); \
        bf16* _dB = (bf16*)(smem + ((p) ^ 1) * 32768 + 16384 + wave * 2048); \
        async_cp16(aSrc, _dA);       async_cp16(aSrc + sq8, _dA + 512); \
        async_cp16(bSrc, _dB);       async_cp16(bSrc + sq8, _dB + 512); \
        aSrc += 64; bSrc += 64; \
    } \
    asm volatile("s_waitcnt lgkmcnt(4)"); \
    __builtin_amdgcn_sched_barrier(0); \
    __builtin_amdgcn_s_setprio(1); \
    MM8(0); \
    __builtin_amdgcn_s_setprio(0); \
    asm volatile("s_waitcnt lgkmcnt(0)"); \
    __builtin_amdgcn_sched_barrier(0); \
    __builtin_amdgcn_s_setprio(1); \
    MM8(1); \
    __builtin_amdgcn_s_setprio(0); \
    __builtin_amdgcn_sched_barrier(0); \
    asm volatile("s_waitcnt vmcnt(0)"); \
    __builtin_amdgcn_s_barrier(); \
} while (0)

    const int NT = K >> 6, NH = NT >> 1;

    // prologue: stage tile 0 into buf0; sources then point at tile 1
    {
        bf16* dA = (bf16*)(smem + wave * 2048);
        bf16* dB = (bf16*)(smem + 16384 + wave * 2048);
        async_cp16(aSrc, dA);       async_cp16(aSrc + sq8, dA + 512);
        async_cp16(bSrc, dB);       async_cp16(bSrc + sq8, dB + 512);
        aSrc += 64; bSrc += 64;
    }

    f32x4 acc[4][2];
    {
        const f32x4 zf = {0.f, 0.f, 0.f, 0.f};
        #pragma unroll
        for (int i = 0; i < 4; i++) {
            acc[i][0] = zf; acc[i][1] = zf;
        }
    }
    bf16x8 av[8], bv[4];

    asm volatile("s_waitcnt vmcnt(0)");
    __builtin_amdgcn_s_barrier();

    for (int it = 0; it < NH; ++it) {
        const bool so = (it + 1 < NH);
        TILE(0, true);     // tile 2it   (buf0); stage 2it+1 -> buf1
        TILE(1, so);       // tile 2it+1 (buf1); stage 2it+2 -> buf0
    }
#undef TILE
#undef MM8
#undef DSR

    // epilogue: 2 passes of 64 rows through LDS
    float* sC = (float*)smem;
    const int q4 = lane >> 4;
    const int lr = tid >> 3;            // 0..63
    const int c0 = (tid & 7) * 4;
    const long long Nll = N;
    #pragma unroll
    for (int p2 = 0; p2 < 2; p2++) {
        __syncthreads();
        if (wm == p2) {
            #pragma unroll
            for (int mi = 0; mi < 4; mi++)
                #pragma unroll
                for (int r = 0; r < 4; r++) {
                    const int row = mi * 16 + q4 * 4 + r;
                    #pragma unroll
                    for (int ni = 0; ni < 2; ni++)
                        sC[row * 132 + wn * 32 + ni * 16 + fr] = acc[mi][ni][r];
                }
        }
        __syncthreads();
        const long long grow = m0 + p2 * 64 + lr;
        const long long gb = grow * Nll + n0;
        const float* srow = sC + lr * 132;
        #pragma unroll
        for (int g = 0; g < 4; g++) {
            const int col = c0 + g * 32;
            f32x4 v = *(const f32x4*)(srow + col);
            float vv[4] = {v[0], v[1], v[2], v[3]};
            if (bon) {
                bf16x4 bb = *(const bf16x4*)(biasz + n0 + col);
                #pragma unroll
                for (int j = 0; j < 4; j++) vv[j] = vv[j] * scale + (float)bb[j];
            } else {
                #pragma unroll
                for (int j = 0; j < 4; j++) vv[j] *= scale;
            }
            if constexpr (ACT == 1) {
                #pragma unroll
                for (int j = 0; j < 4; j++) vv[j] = gelu_fast(vv[j]);
            }
            if (ron) {
                bf16x4 rr = *(const bf16x4*)(res + gb + col);
                #pragma unroll
                for (int j = 0; j < 4; j++) vv[j] += (float)rr[j];
            }
            if constexpr (OUT_F32) {
                f32x4 o4 = {vv[0], vv[1], vv[2], vv[3]};
                *(f32x4*)((float*)Cb + coff + gb + col) = o4;
            } else {
                bf16x4 o4;
                #pragma unroll
                for (int j = 0; j < 4; j++) o4[j] = (bf16)vv[j];
                *(bf16x4*)((bf16*)Cb + coff + gb + col) = o4;
            }
        }
    }
}

// --- softmax / layernorm ----------------------------------------------------

__global__ __launch_bounds__(256)
void softmax_inplace(bf16* __restrict__ P, int N)
{
    const long long row = blockIdx.x;
    bf16* p = P + row * (long long)N;
    const int t = threadIdx.x;
    bf16x4 xin = *(const bf16x4*)(p + t * 4);
    float xs[4];
    #pragma unroll
    for (int i = 0; i < 4; i++) xs[i] = (float)xin[i];

    float m = fmaxf(fmaxf(xs[0], xs[1]), fmaxf(xs[2], xs[3]));
    #pragma unroll
    for (int off = 32; off > 0; off >>= 1) m = fmaxf(m, __shfl_xor(m, off, 64));
    __shared__ float red[4];
    if ((t & 63) == 0) red[t >> 6] = m;
    __syncthreads();
    m = fmaxf(fmaxf(red[0], red[1]), fmaxf(red[2], red[3]));

    float e[4], s = 0.f;
    #pragma unroll
    for (int i = 0; i < 4; i++) { e[i] = __expf(xs[i] - m); s += e[i]; }
    #pragma unroll
    for (int off = 32; off > 0; off >>= 1) s += __shfl_xor(s, off, 64);
    __shared__ float red2[4];
    if ((t & 63) == 0) red2[t >> 6] = s;
    __syncthreads();
    s = red2[0] + red2[1] + red2[2] + red2[3];
    const float inv = 1.f / s;

    bf16x4 o;
    #pragma unroll
    for (int i = 0; i < 4; i++) o[i] = (bf16)(e[i] * inv);
    *(bf16x4*)(p + t * 4) = o;
}

// IN_MODE: 0 = bf16, 1 = f32, 2 = f32+f32 (split-K), 3 = bf16+bf16 (split-K)
template<int IN_MODE, int OUT_F32>
__global__ __launch_bounds__(256)
void layernorm_rows(const void* __restrict__ Z, const void* __restrict__ Z2,
                    const bf16* __restrict__ g, const bf16* __restrict__ b,
                    void* __restrict__ outp, int N)
{
    const long long row = blockIdx.x;
    const int t = threadIdx.x;
    float xv[4];
    if constexpr (IN_MODE == 1 || IN_MODE == 2) {
        f32x4 zin = *(const f32x4*)((const float*)Z + row * (long long)N + t * 4);
        #pragma unroll
        for (int i = 0; i < 4; i++) xv[i] = zin[i];
        if constexpr (IN_MODE == 2) {
            f32x4 z2 = *(const f32x4*)((const float*)Z2 + row * (long long)N + t * 4);
            #pragma unroll
            for (int i = 0; i < 4; i++) xv[i] += z2[i];
        }
    } else {
        bf16x4 zin = *(const bf16x4*)((const bf16*)Z + row * (long long)N + t * 4);
        #pragma unroll
        for (int i = 0; i < 4; i++) xv[i] = (float)zin[i];
        if constexpr (IN_MODE == 3) {
            bf16x4 z2 = *(const bf16x4*)((const bf16*)Z2 + row * (long long)N + t * 4);
            #pragma unroll
            for (int i = 0; i < 4; i++) xv[i] += (float)z2[i];
        }
    }

    float s = xv[0] + xv[1] + xv[2] + xv[3];
    #pragma unroll
    for (int off = 32; off > 0; off >>= 1) s += __shfl_xor(s, off, 64);
    __shared__ float r1[4];
    if ((t & 63) == 0) r1[t >> 6] = s;
    __syncthreads();
    const float mu = (r1[0] + r1[1] + r1[2] + r1[3]) * (1.f / 1024.f);

    float d[4];
    float sq = 0.f;
    #pragma unroll
    for (int i = 0; i < 4; i++) { d[i] = xv[i] - mu; sq += d[i] * d[i]; }
    #pragma unroll
    for (int off = 32; off > 0; off >>= 1) sq += __shfl_xor(sq, off, 64);
    __shared__ float r2[4];
    if ((t & 63) == 0) r2[t >> 6] = sq;
    __syncthreads();
    const float var = (r2[0] + r2[1] + r2[2] + r2[3]) * (1.f / 1024.f);
    const float rstd = rsqrtf(var + 1e-12f);

    bf16x4 gv = *(const bf16x4*)(g + t * 4);
    bf16x4 bv = *(const bf16x4*)(b + t * 4);
    if constexpr (OUT_F32) {
        f32x4 o;
        #pragma unroll
        for (int i = 0; i < 4; i++)
            o[i] = d[i] * rstd * (float)gv[i] + (float)bv[i];
        *(f32x4*)((float*)outp + row * (long long)N + t * 4) = o;
    } else {
        bf16x4 o;
        #pragma unroll
        for (int i = 0; i < 4; i++)
            o[i] = (bf16)(d[i] * rstd * (float)gv[i] + (float)bv[i]);
        *(bf16x4*)((bf16*)outp + row * (long long)N + t * 4) = o;
    }
}

// --- driver -----------------------------------------------------------------

extern "C" void kernel_launch(void* const* d_in, const int* in_sizes, int n_in,
                              void* d_out, int out_size, void* d_ws, size_t ws_size,
                              hipStream_t stream)
{
    (void)in_sizes; (void)n_in; (void)out_size;

    const void* x  = d_in[0];
    const void* Wq = d_in[1];  const void* bq = d_in[2];
    const void* Wk = d_in[3];  const void* bk = d_in[4];
    const void* Wv = d_in[5];  const void* bv = d_in[6];
    const void* Wd = d_in[7];  const void* bd = d_in[8];
    const void* g1 = d_in[9];  const void* b1 = d_in[10];
    const void* Wi = d_in[11]; const void* bi = d_in[12];
    const void* Wo = d_in[13]; const void* bo = d_in[14];
    const void* g2 = d_in[15]; const void* b2 = d_in[16];

    const int Bb = 8, S = 1024, E = 1024, F = 4096;
    const int M = Bb * S;                         // 8192
    const long long SE = (long long)S * E, SS = (long long)S * S;
    const long long ME = (long long)M * E;

    char* ws = (char*)d_ws;
    const size_t MB = 1024ull * 1024ull;
    int*  dflag = (int*)(ws + 0);
    bf16* small = (bf16*)(ws + 64 * 1024);
    bf16* bq_c = small + 0 * 1024;                 // bq,bk,bv contiguous
    bf16* bd_c = small + 3 * 1024;
    bf16* g1_c = small + 4 * 1024;
    bf16* b1_c = small + 5 * 1024;
    bf16* g2_c = small + 6 * 1024;
    bf16* b2_c = small + 7 * 1024;
    bf16* bo_c = small + 8 * 1024;
    bf16* bi_c = small + 9216;
    bf16* WoT  = (bf16*)(ws + 1 * MB);    // [E,F] 8MB, live to z2
    bf16* WiT  = (bf16*)(ws + 9 * MB);    // [F,E] 8MB, live to ff
    bf16* WqT  = (bf16*)(ws + 17 * MB);   // Wq/Wk/Wv/Wd contiguous [4][E][E]
    bf16* WkT  = (bf16*)(ws + 19 * MB);
    bf16* WvT  = (bf16*)(ws + 21 * MB);
    bf16* WdT  = (bf16*)(ws + 23 * MB);
    bf16* xb   = (bf16*)(ws + 25 * MB);   // [M,E] 16MB, live to z1
    float* out = (float*)d_out;

    diag_init<<<1, 64, 0, stream>>>(x, dflag);

    if (ws_size < 70 * MB) { sentinel_small<<<1, 1, 0, stream>>>(out); return; }

    SmallPtrs sp;
    sp.p[0] = bq; sp.p[1] = bk; sp.p[2] = bv; sp.p[3] = bd; sp.p[4] = g1;
    sp.p[5] = b1; sp.p[6] = g2; sp.p[7] = b2; sp.p[8] = bo; sp.p[9] = bi;
    convert_small<<<52, 256, 0, stream>>>(sp, small, dflag);
    convert_vec4<<<8192, 256, 0, stream>>>(x, xb, ME / 4, dflag);

    const dim3 tb(32, 8, 1);
    W4Ptrs wp; wp.p[0] = Wq; wp.p[1] = Wk; wp.p[2] = Wv; wp.p[3] = Wd;
    transpose_quad<<<dim3(E/32, E/32, 4), tb, 0, stream>>>(wp, WqT, E, E, dflag);
    transpose_dual<<<dim3(F/32, E/32), tb, 0, stream>>>(Wi, WiT, E, F, dflag);
    transpose_dual<<<dim3(E/32, F/32), tb, 0, stream>>>(Wo, WoT, F, E, dflag);

    if (ws_size >= 121 * MB) {
        // ---- batched path ----
        bf16* qkv  = (bf16*)(ws + 41 * MB);   // [3][M,E] 48MB contiguous
        bf16* q    = qkv;
        bf16* k    = qkv + ME;
        bf16* v    = qkv + 2 * ME;
        bf16* vT   = (bf16*)(ws + 89 * MB);   // [B,E,S] 16MB
        bf16* P    = (bf16*)(ws + 73 * MB);   // over v (dead after vT)
        bf16* attn = (bf16*)(ws + 41 * MB);   // over q (dead after scores)
        bf16* z1   = (bf16*)(ws + 57 * MB);   // over k (dead after scores)
        bf16* h1   = (bf16*)(ws + 41 * MB);   // over attn (dead after z1)
        bf16* ff   = (bf16*)(ws + 57 * MB);   // 64MB, spans 57..121 (z1/P/vT dead)
        bf16* z2a  = (bf16*)(ws + 9 * MB);    // 16MB over WiT (dead after FF)
        bf16* z2b  = (bf16*)(ws + 25 * MB);   // 16MB over xb (dead after Wd)

        // QKV: 256^2 (measured best), z=3 batched weights
        gemm256<0,1,0,0,0><<<dim3((E/256)*(M/256), 3), 512, 0, stream>>>(
            xb, WqT, bq_c, nullptr, qkv, nullptr, M, E, E, E, 1.f,
            (long long)E * E, ME, E);
        transpose_b<<<dim3(E/32, S/32, Bb), tb, 0, stream>>>(v, vT, S, E);
        // scores: 128^2, z=8 batches
        gemm128d<0,0,0,0,0><<<dim3((S/128)*(S/128), Bb), 512, 0, stream>>>(
            q, k, nullptr, nullptr, P, nullptr, S, S, E, E, 0.03125f,
            SE, SE, SS, 0);
        softmax_inplace<<<M, 256, 0, stream>>>(P, S);
        // PV: 128^2, z=8 batches
        gemm128d<0,0,0,0,0><<<dim3((E/128)*(S/128), Bb), 512, 0, stream>>>(
            P, vT, nullptr, nullptr, attn, nullptr, S, E, S, S, 1.f,
            SS, SE, SE, 0);
        // Wd + residual: 128^2
        gemm128d<0,1,1,0,0><<<dim3((E/128)*(M/128), 1), 512, 0, stream>>>(
            attn, WdT, bd_c, xb, z1, nullptr, M, E, E, E, 1.f, 0, 0, 0, 0);
        layernorm_rows<0,0><<<M, 256, 0, stream>>>(z1, nullptr, g1_c, b1_c, h1, E);
        // FF: 256^2 (measured best), gelu fused
        gemm256<1,1,0,0,0><<<dim3((F/256)*(M/256), 1), 512, 0, stream>>>(
            h1, WiT, bi_c, nullptr, ff, nullptr, M, F, E, E, 1.f, 0, 0, 0);
        // Wo: 256^2 split-K=2 (256 blocks = exact fill); bf16 partials at
        // race-free offsets (z2a over dead WiT, z2b over dead xb).
        // chunk0 carries bias + residual(h1).
        gemm256<0,1,1,0,1><<<dim3((E/256)*(M/256), 2), 512, 0, stream>>>(
            ff, WoT, bo_c, h1, z2a, z2b, M, E, F / 2, F, 1.f, 0, 0, 0);
        layernorm_rows<3,1><<<M, 256, 0, stream>>>(z2a, z2b, g2_c, b2_c, out, E);
    } else {
        // ---- fallback: per-batch (peak 67MB), z2 in bf16 ----
        bf16* qkv_b = (bf16*)(ws + 41 * MB);  // [3][S,E] 6MB contiguous
        bf16* q_b   = qkv_b;
        bf16* k_b   = qkv_b + SE;
        bf16* v_b   = qkv_b + 2 * SE;
        bf16* vT_b  = (bf16*)(ws + 47 * MB);
        bf16* P_b   = (bf16*)(ws + 49 * MB);
        bf16* at_b  = (bf16*)(ws + 51 * MB);
        bf16* z1_b  = (bf16*)(ws + 53 * MB);
        bf16* h1_b  = (bf16*)(ws + 55 * MB);
        bf16* ff_b  = (bf16*)(ws + 57 * MB);  // 8MB
        bf16* z2_b  = (bf16*)(ws + 65 * MB);  // 2MB

        for (int b = 0; b < Bb; b++) {
            const bf16* x_b = xb + (long long)b * SE;
            gemm_bt<0,1,0,0><<<dim3(8, 8, 3), 512, 0, stream>>>(
                x_b, WqT, bq_c, nullptr, qkv_b, S, E, E, 1.f, 0, (long long)E * E, SE, E);
            transpose_b<<<dim3(E/32, S/32), tb, 0, stream>>>(v_b, vT_b, S, E);
            gemm_bt<0,0,0,0><<<dim3(8, 8), 512, 0, stream>>>(
                q_b, k_b, nullptr, nullptr, P_b, S, S, E, 0.03125f, 0, 0, 0, 0);
            softmax_inplace<<<S, 256, 0, stream>>>(P_b, S);
            gemm_bt<0,0,0,0><<<dim3(8, 8), 512, 0, stream>>>(
                P_b, vT_b, nullptr, nullptr, at_b, S, E, S, 1.f, 0, 0, 0, 0);
            gemm_bt<0,1,1,0><<<dim3(8, 8), 512, 0, stream>>>(
                at_b, WdT, bd_c, x_b, z1_b, S, E, E, 1.f, 0, 0, 0, 0);
            layernorm_rows<0,0><<<S, 256, 0, stream>>>(z1_b, nullptr, g1_c, b1_c, h1_b, E);
            gemm_bt<1,1,0,0><<<dim3(32, 8), 512, 0, stream>>>(
                h1_b, WiT, bi_c, nullptr, ff_b, S, F, E, 1.f, 0, 0, 0, 0);
            gemm_bt<0,1,1,0><<<dim3(8, 8), 512, 0, stream>>>(
                ff_b, WoT, bo_c, h1_b, z2_b, S, E, F, 1.f, 0, 0, 0, 0);
            layernorm_rows<0,1><<<S, 256, 0, stream>>>(z2_b, nullptr, g2_c, b2_c, out + (long long)b * SE, E);
        }
    }
}

// Round 10
// 468.403 us; speedup vs baseline: 1.0300x; 1.0300x over previous
//
#include <hip/hip_runtime.h>
#include <math.h>

// ---------------------------------------------------------------------------
// BertLayer forward on gfx950. Round 20: QKV back to gemm128d (grid fill).
// Established: inputs fp32, output fp32, bf16-emulated ref (thr 0.10625).
// vs r19 (PASS 482us, absmax 0.047; Wo split-K on gemm256 now <82us vs 97,
// but QKV on gemm256 = 384 blocks @ 1/CU = 1.5 rounds -> ~82us, canceling
// the FF win; r16's QKV on gemm128d = 1536 blocks @ 2/CU = 3 exact rounds
// = 72.6us):
//   Assignment rule from measurements: gemm256 only when grid is a multiple
//   of 256 blocks (FF 512 = 2 rounds; Wo split-K 256 = 1 round); gemm128d
//   otherwise (QKV 1536@2/CU, scores/PV/Wd 512@2/CU = exact fills).
//   r20 = r19 with QKV on gemm128d (r16-verified call, verbatim).
// ---------------------------------------------------------------------------

typedef __bf16 bf16;
typedef __attribute__((ext_vector_type(8))) __bf16 bf16x8;
typedef __attribute__((ext_vector_type(4))) __bf16 bf16x4;
typedef __attribute__((ext_vector_type(4))) float f32x4;

#define BM 128
#define BN 128
#define BK 64
#define SCS 140   // epilogue LDS row stride (floats) for old kernel

__device__ __forceinline__ void async_cp16(const bf16* g, bf16* l) {
    __builtin_amdgcn_global_load_lds((__attribute__((address_space(1))) void*)(g),
                                     (__attribute__((address_space(3))) void*)(l),
                                     16, 0, 0);
}

// gelu(x) ~= x * sigmoid(1.59577*x*(1+0.044715*x^2)); max abs err ~3e-3.
__device__ __forceinline__ float gelu_fast(float x) {
    float u = x * x;
    float y = 1.5957691216f * x * fmaf(0.044715f, u, 1.0f);
    float e = __expf(-y);
    return x * __builtin_amdgcn_rcpf(1.0f + e);
}

__device__ __forceinline__ float load_dual(const void* p, long long i, int f32) {
    return f32 ? ((const float*)p)[i] : (float)((const bf16*)p)[i];
}

// --- dtype detect / sentinel ------------------------------------------------

__global__ void diag_init(const void* x, int* dflag)
{
    const int t = threadIdx.x;            // 0..63
    const bf16* xb = (const bf16*)x;
    float a = (float)xb[2 * t];
    float b = (float)xb[2 * t + 1];
    auto wild = [](float v) -> bool {
        float af = fabsf(v);
        return !(af <= 3.0e38f) || af > 1.0e3f || (v != 0.0f && af < 1.0e-8f);
    };
    unsigned long long ba = __ballot(wild(a));
    unsigned long long bb = __ballot(wild(b));
    if (t == 0) *dflag = (__popcll(ba) + __popcll(bb) > 16) ? 1 : 0;
}

__global__ void sentinel_small(float* out) { out[0] = 2048.0f; }

// --- input normalization ----------------------------------------------------

__global__ __launch_bounds__(256)
void convert_vec4(const void* src, bf16* dst, long long n4, const int* dflag)
{
    const int f32 = *dflag;
    long long i = (long long)blockIdx.x * 256 + threadIdx.x;
    if (i >= n4) return;
    bf16x4 o;
    if (f32) {
        f32x4 v = ((const f32x4*)src)[i];
        #pragma unroll
        for (int j = 0; j < 4; j++) o[j] = (bf16)v[j];
    } else {
        o = ((const bf16x4*)src)[i];
    }
    ((bf16x4*)dst)[i] = o;
}

struct SmallPtrs { const void* p[10]; };   // 9x E vectors + 1x F vector

__global__ __launch_bounds__(256)
void convert_small(SmallPtrs sp, bf16* dst, const int* dflag)
{
    const int f32 = *dflag;
    const int idx = blockIdx.x * 256 + threadIdx.x;   // 0..13311
    if (idx >= 13312) return;
    const int seg = idx >> 10;
    float v;
    if (seg < 9) v = load_dual(sp.p[seg], idx & 1023, f32);
    else         v = load_dual(sp.p[9], idx - 9216, f32);
    dst[idx] = (bf16)v;
}

__global__ __launch_bounds__(256)
void transpose_dual(const void* in, bf16* out, int R, int C, const int* dflag)
{
    __shared__ bf16 tile[32][33];
    const int f32 = *dflag;
    const int c0 = blockIdx.x * 32, r0 = blockIdx.y * 32;
    const int tx = threadIdx.x, ty = threadIdx.y;
    #pragma unroll
    for (int i = 0; i < 32; i += 8)
        tile[ty + i][tx] = (bf16)load_dual(in, (long long)(r0 + ty + i) * C + (c0 + tx), f32);
    __syncthreads();
    #pragma unroll
    for (int i = 0; i < 32; i += 8)
        out[(long long)(c0 + ty + i) * R + (r0 + tx)] = tile[tx][ty + i];
}

struct W4Ptrs { const void* p[4]; };

// 4 same-shape square transposes in one launch (z selects matrix).
__global__ __launch_bounds__(256)
void transpose_quad(W4Ptrs wp, bf16* outbase, int R, int C, const int* dflag)
{
    __shared__ bf16 tile[32][33];
    const int f32 = *dflag;
    const void* in = wp.p[blockIdx.z];
    bf16* out = outbase + (long long)blockIdx.z * (long long)R * C;
    const int c0 = blockIdx.x * 32, r0 = blockIdx.y * 32;
    const int tx = threadIdx.x, ty = threadIdx.y;
    #pragma unroll
    for (int i = 0; i < 32; i += 8)
        tile[ty + i][tx] = (bf16)load_dual(in, (long long)(r0 + ty + i) * C + (c0 + tx), f32);
    __syncthreads();
    #pragma unroll
    for (int i = 0; i < 32; i += 8)
        out[(long long)(c0 + ty + i) * R + (r0 + tx)] = tile[tx][ty + i];
}

__global__ __launch_bounds__(256)
void transpose_b(const bf16* __restrict__ in, bf16* __restrict__ out, int R, int C)
{
    __shared__ bf16 tile[32][33];
    const long long z = (long long)blockIdx.z * (long long)R * C;
    const int c0 = blockIdx.x * 32, r0 = blockIdx.y * 32;
    const int tx = threadIdx.x, ty = threadIdx.y;
    #pragma unroll
    for (int i = 0; i < 32; i += 8)
        tile[ty + i][tx] = in[z + (long long)(r0 + ty + i) * C + (c0 + tx)];
    __syncthreads();
    #pragma unroll
    for (int i = 0; i < 32; i += 8)
        out[z + (long long)(c0 + ty + i) * R + (r0 + tx)] = tile[tx][ty + i];
}

// --- GEMM 128^2: producer-consumer (fallback path only) ---------------------
template<int ACT, int HAS_BIAS, int HAS_RES, int OUT_F32>
__global__ __launch_bounds__(512)
void gemm_bt(const bf16* __restrict__ A, const bf16* __restrict__ Bt,
             const bf16* __restrict__ bias, const bf16* __restrict__ res,
             void* __restrict__ Cout, int M, int N, int K, float scale,
             long long bsA, long long bsB, long long bsC, long long bsBias)
{
    __shared__ __align__(16) char smem[65536];   // 2 x (sA 16KB + sB 16KB)
    float* sC = (float*)smem;                    // epilogue [64][SCS]

    const int tid  = threadIdx.x;
    const int lane = tid & 63;
    const int wave = tid >> 6;          // 0..7
    const int pw   = wave & 3;
    const int wm   = pw >> 1;
    const int wn   = pw & 1;
    const bool producer = (wave >= 4);
    const int m0   = blockIdx.y * BM;
    const int n0   = blockIdx.x * BN;
    const long long zA = (long long)blockIdx.z * bsA;
    const long long zB = (long long)blockIdx.z * bsB;
    const long long zC = (long long)blockIdx.z * bsC;
    const bf16* biasz = HAS_BIAS ? (bias + (long long)blockIdx.z * bsBias) : nullptr;
    const int nIter = K >> 6;

    f32x4 acc[4][4];
    const bf16* gA[4]; const bf16* gB[4]; int lo[4];

    if (producer) {
        #pragma unroll
        for (int j = 0; j < 4; j++) {
            const int ci  = j * 256 + pw * 64 + lane;
            const int row = ci >> 3;
            const int c8  = ((ci & 7) ^ (row & 7)) * 8;   // swizzle
            gA[j] = A + zA + (long long)(m0 + row) * K + c8;
            gB[j] = Bt + zB + (long long)(n0 + row) * K + c8;
            lo[j] = (j * 256 + pw * 64) * 8;              // element offset
        }
        bf16* dA = (bf16*)smem;
        bf16* dB = (bf16*)(smem + 16384);
        #pragma unroll
        for (int j = 0; j < 4; j++) {
            async_cp16(gA[j], dA + lo[j]);
            async_cp16(gB[j], dB + lo[j]);
            gA[j] += BK; gB[j] += BK;
        }
    } else {
        const f32x4 zf = {0.f, 0.f, 0.f, 0.f};
        #pragma unroll
        for (int i = 0; i < 4; i++)
            #pragma unroll
            for (int j = 0; j < 4; j++) acc[i][j] = zf;
    }
    __syncthreads();

    const int fr   = lane & 15;
    const int x0   = (lane >> 4) ^ (fr & 7);
    const int arow = wm * 64 + fr;
    const int brow = wn * 64 + fr;

    for (int kt = 0; kt < nIter; ++kt) {
        if (producer) {
            if (kt + 1 < nIter) {
                const int bo = ((kt + 1) & 1) ? 32768 : 0;
                bf16* dA = (bf16*)(smem + bo);
                bf16* dB = (bf16*)(smem + bo + 16384);
                #pragma unroll
                for (int j = 0; j < 4; j++) {
                    async_cp16(gA[j], dA + lo[j]);
                    async_cp16(gB[j], dB + lo[j]);
                    gA[j] += BK; gB[j] += BK;
                }
            }
        } else {
            const int bo = (kt & 1) ? 32768 : 0;
            const bf16* sAk = (const bf16*)(smem + bo);
            const bf16* sBk = (const bf16*)(smem + bo + 16384);
            #pragma unroll
            for (int s = 0; s < 2; s++) {
                const int xo = (x0 ^ (s << 2)) * 8;
                bf16x8 afr[4], bfr[4];
                #pragma unroll
                for (int mi = 0; mi < 4; mi++) afr[mi] = *(const bf16x8*)(sAk + (arow + mi * 16) * 64 + xo);
                #pragma unroll
                for (int ni = 0; ni < 4; ni++) bfr[ni] = *(const bf16x8*)(sBk + (brow + ni * 16) * 64 + xo);
                #pragma unroll
                for (int mi = 0; mi < 4; mi++)
                    #pragma unroll
                    for (int ni = 0; ni < 4; ni++)
                        acc[mi][ni] = __builtin_amdgcn_mfma_f32_16x16x32_bf16(afr[mi], bfr[ni], acc[mi][ni], 0, 0, 0);
            }
        }
        __syncthreads();
    }

    const int q4 = lane >> 4;
    for (int h = 0; h < 2; h++) {
        __syncthreads();
        if (!producer && wm == h) {
            #pragma unroll
            for (int mi = 0; mi < 4; mi++)
                #pragma unroll
                for (int r = 0; r < 4; r++) {
                    const int lr = mi * 16 + q4 * 4 + r;
                    #pragma unroll
                    for (int ni = 0; ni < 4; ni++)
                        sC[lr * SCS + wn * 64 + ni * 16 + fr] = acc[mi][ni][r];
                }
        }
        __syncthreads();
        const int lr = tid >> 3;             // 0..63
        const int cb = (tid & 7) * 16;       // 0..112
        const long long grow  = m0 + h * 64 + lr;
        const long long gbase = zC + grow * (long long)N + (n0 + cb);
        const float* srow = sC + lr * SCS + cb;
        #pragma unroll
        for (int g = 0; g < 2; g++) {
            f32x4 v0 = *(const f32x4*)(srow + g * 8);
            f32x4 v1 = *(const f32x4*)(srow + g * 8 + 4);
            float vv[8] = {v0[0], v0[1], v0[2], v0[3], v1[0], v1[1], v1[2], v1[3]};
            if constexpr (HAS_BIAS) {
                bf16x8 bb = *(const bf16x8*)(biasz + n0 + cb + g * 8);
                #pragma unroll
                for (int j = 0; j < 8; j++) vv[j] = vv[j] * scale + (float)bb[j];
            } else {
                #pragma unroll
                for (int j = 0; j < 8; j++) vv[j] *= scale;
            }
            if constexpr (ACT == 1) {
                #pragma unroll
                for (int j = 0; j < 8; j++) vv[j] = gelu_fast(vv[j]);
            }
            if constexpr (HAS_RES) {
                bf16x8 rr = *(const bf16x8*)(res + gbase + g * 8);
                #pragma unroll
                for (int j = 0; j < 8; j++) vv[j] += (float)rr[j];
            }
            if constexpr (OUT_F32) {
                f32x4 o0 = {vv[0], vv[1], vv[2], vv[3]};
                f32x4 o1 = {vv[4], vv[5], vv[6], vv[7]};
                *(f32x4*)((float*)Cout + gbase + g * 8)     = o0;
                *(f32x4*)((float*)Cout + gbase + g * 8 + 4) = o1;
            } else {
                bf16x8 o;
                #pragma unroll
                for (int j = 0; j < 8; j++) o[j] = (bf16)vv[j];
                *(bf16x8*)((bf16*)Cout + gbase + g * 8) = o;
            }
        }
    }
}

// --- GEMM 256x256, 8-phase, row-half staging + quadrant phases (r14) --------
// Used when grid is a multiple of 256 blocks (FF 512, Wo split-K 256).
template<int ACT, int HAS_BIAS, int HAS_RES, int OUT_F32, int SPLITK>
__global__ __launch_bounds__(512, 2)
void gemm256(const bf16* __restrict__ A, const bf16* __restrict__ Bt,
             const bf16* __restrict__ bias, const bf16* __restrict__ res,
             void* __restrict__ Cout, void* __restrict__ Cout2,
             int M, int N, int K, int ldk, float scale,
             long long bsB, long long bsC, long long bsBias)
{
    __shared__ __align__(16) char smem[131072];

    const int tid  = threadIdx.x;
    const int lane = tid & 63;
    const int wave = tid >> 6;          // 0..7
    const int wm   = wave >> 2;         // 0..1
    const int wn   = wave & 3;          // 0..3

    // bijective XCD swizzle on flat workgroup id (m204 variant)
    const int gx  = N >> 8;
    const int nwg = gx * (M >> 8);
    int wg = blockIdx.x;
    {
        const int q = nwg >> 3, r = nwg & 7;
        const int xcd = wg & 7, lid = wg >> 3;
        wg = (xcd < r ? xcd * (q + 1) : r * (q + 1) + (xcd - r) * q) + lid;
    }
    const int bx = wg % gx, by = wg / gx;
    const int m0 = by << 8, n0 = bx << 8;
    const int zi = blockIdx.y;          // batch (SPLITK=0) or k-chunk (=1)

    const bf16* Ab = A  + (SPLITK ? (long long)zi * K : 0);
    const bf16* Bb = Bt + (SPLITK ? (long long)zi * K : (long long)zi * bsB);
    const bool  bon = HAS_BIAS && (!SPLITK || zi == 0);
    const bool  ron = HAS_RES  && (!SPLITK || zi == 0);
    const bf16* biasz = HAS_BIAS ? (bias + (SPLITK ? 0 : (long long)zi * bsBias)) : nullptr;
    const long long coff = SPLITK ? 0 : (long long)zi * bsC;
    char* const Cb = (char*)((SPLITK && zi) ? Cout2 : Cout);

    // DMA source addressing (inverse of LDS granule permutation)
    const int rg0 = wave * 16 + (lane >> 3);       // row within half [0,128)
    const int cg0 = (lane & 7) ^ (lane >> 3);      // granule column 0..7
    const bf16* aSrc[2]; const bf16* bSrc[2];
    #pragma unroll
    for (int h = 0; h < 2; h++) {
        aSrc[h] = Ab + (long long)(m0 + h * 128 + rg0) * ldk + cg0 * 8;
        bSrc[h] = Bb + (long long)(n0 + h * 128 + rg0) * ldk + cg0 * 8;
    }
    const int sq8 = 8 * ldk;                       // qq=1: row+8, same c

    // ds_read byte addresses: aAddr/bAddr[buf*2+kk]
    const int fr = lane & 15, chk = lane >> 4;
    unsigned aAddr[4], bAddr[4];
    {
        const unsigned sm3 = (unsigned)(size_t)(__attribute__((address_space(3))) char*)smem;
        #pragma unroll
        for (int cb = 0; cb < 2; cb++)
            #pragma unroll
            for (int kk = 0; kk < 2; kk++) {
                const unsigned slot = (unsigned)(((kk * 4 + chk) ^ (fr & 7)) * 16);
                aAddr[cb * 2 + kk] = sm3 + cb * 65536 + wm * 16384
                                   + fr * 128 + slot;
                bAddr[cb * 2 + kk] = sm3 + cb * 65536 + 32768 + (wn >> 1) * 16384
                                   + ((wn & 1) * 64 + fr) * 128 + slot;
            }
    }

#define DSR(d, b, imm) \
    asm volatile("ds_read_b128 %0, %1 offset:%c2" : "=v"(d) : "v"(b), "i"(imm))
// A quadrant q reads: set[0]=(i0,kk0) set[1]=(i0,kk1) set[2]=(i1,kk0) set[3]=(i1,kk1)
#define RDA4(set, cb, q) do { \
    DSR(set[0], aAddr[(cb) * 2 + 0], (q) * 4096); \
    DSR(set[1], aAddr[(cb) * 2 + 1], (q) * 4096); \
    DSR(set[2], aAddr[(cb) * 2 + 0], (q) * 4096 + 2048); \
    DSR(set[3], aAddr[(cb) * 2 + 1], (q) * 4096 + 2048); \
} while (0)
// B all 4 n-frags x kk: bv[j*2+kk]
#define RDB8(cb) do { \
    DSR(bv[0], bAddr[(cb) * 2 + 0], 0);    DSR(bv[1], bAddr[(cb) * 2 + 1], 0); \
    DSR(bv[2], bAddr[(cb) * 2 + 0], 2048); DSR(bv[3], bAddr[(cb) * 2 + 1], 2048); \
    DSR(bv[4], bAddr[(cb) * 2 + 0], 4096); DSR(bv[5], bAddr[(cb) * 2 + 1], 4096); \
    DSR(bv[6], bAddr[(cb) * 2 + 0], 6144); DSR(bv[7], bAddr[(cb) * 2 + 1], 6144); \
} while (0)
#define STG(buf, mat, h, t) do { \
    bf16* _d = (bf16*)(smem + (buf) * 65536 + (mat) * 32768 + (h) * 16384 + wave * 2048); \
    const bf16* _s = ((mat) ? bSrc[h] : aSrc[h]) + (t) * 64; \
    async_cp16(_s, _d); \
    async_cp16(_s + sq8, _d + 512); \
} while (0)
#define IF_STG(c, buf, mat, h, t) do { if (c) STG(buf, mat, h, t); } while (0)
#define BARR __builtin_amdgcn_s_barrier()
#define SB0  __builtin_amdgcn_sched_barrier(0)
#define LGKM0 asm volatile("s_waitcnt lgkmcnt(0)")
#define VM_WAIT(c) do { \
    if (c) asm volatile("s_waitcnt vmcnt(4)"); \
    else   asm volatile("s_waitcnt vmcnt(0)"); \
} while (0)
// 16 MFMA: kk0 (8 indep), then kk1 (8, each dep on its kk0 partner)
#define MMA(q, ASET) do { \
    __builtin_amdgcn_s_setprio(1); \
    _Pragma("unroll") \
    for (int _j = 0; _j < 4; _j++) { \
        acc[(q) * 2 + 0][_j] = __builtin_amdgcn_mfma_f32_16x16x32_bf16(ASET[0], bv[_j * 2 + 0], acc[(q) * 2 + 0][_j], 0, 0, 0); \
        acc[(q) * 2 + 1][_j] = __builtin_amdgcn_mfma_f32_16x16x32_bf16(ASET[2], bv[_j * 2 + 0], acc[(q) * 2 + 1][_j], 0, 0, 0); \
    } \
    _Pragma("unroll") \
    for (int _j = 0; _j < 4; _j++) { \
        acc[(q) * 2 + 0][_j] = __builtin_amdgcn_mfma_f32_16x16x32_bf16(ASET[1], bv[_j * 2 + 1], acc[(q) * 2 + 0][_j], 0, 0, 0); \
        acc[(q) * 2 + 1][_j] = __builtin_amdgcn_mfma_f32_16x16x32_bf16(ASET[3], bv[_j * 2 + 1], acc[(q) * 2 + 1][_j], 0, 0, 0); \
    } \
    __builtin_amdgcn_s_setprio(0); \
} while (0)

    const int NT = K >> 6, NI = NT >> 1;

    // prologue: tile0 A+B (buf0) + tile1 B (buf1); A(t1) staged at e-q0/q1
    STG(0, 0, 0, 0); STG(0, 0, 1, 0); STG(0, 1, 0, 0); STG(0, 1, 1, 0);
    STG(1, 1, 0, 1); STG(1, 1, 1, 1);

    f32x4 acc[8][4];
    {
        const f32x4 zf = {0.f, 0.f, 0.f, 0.f};
        #pragma unroll
        for (int i = 0; i < 8; i++)
            #pragma unroll
            for (int j = 0; j < 4; j++) acc[i][j] = zf;
    }
    bf16x8 avA[4], avB[4], bv[8];

    asm volatile("s_waitcnt vmcnt(4)");   // drain tile0, allow B(t1) in flight
    BARR;

    for (int it = 0; it < NI; ++it) {
        const int o = 2 * it + 1, e2 = 2 * it + 2, o2 = 2 * it + 3;
        const bool se = e2 < NT, so = o2 < NT;
        // ===== tile e = 2*it in buf0 =====
        // q0: serial B(8)+A(4); stage A-h0(o)
        RDB8(0);
        RDA4(avA, 0, 0);
        STG(1, 0, 0, o);
        BARR; LGKM0; SB0;
        RDA4(avB, 0, 1); SB0;
        MMA(0, avA);
        BARR;
        // q1: stage A-h1(o)
        STG(1, 0, 1, o);
        BARR; LGKM0; SB0;
        RDA4(avA, 0, 2); SB0;
        MMA(1, avB);
        BARR;
        // q2: stage B-h0(e2)
        IF_STG(se, 0, 1, 0, e2);
        BARR; LGKM0; SB0;
        RDA4(avB, 0, 3); SB0;
        MMA(2, avA);
        BARR;
        // q3: stage B-h1(e2); edge
        IF_STG(se, 0, 1, 1, e2);
        BARR; LGKM0; SB0;
        MMA(3, avB); SB0;
        VM_WAIT(se);
        BARR;
        // ===== tile o = 2*it+1 in buf1 =====
        // q0: serial B(8)+A(4); stage A-h0(e2)
        RDB8(1);
        RDA4(avA, 1, 0);
        IF_STG(se, 0, 0, 0, e2);
        BARR; LGKM0; SB0;
        RDA4(avB, 1, 1); SB0;
        MMA(0, avA);
        BARR;
        // q1: stage A-h1(e2)
        IF_STG(se, 0, 0, 1, e2);
        BARR; LGKM0; SB0;
        RDA4(avA, 1, 2); SB0;
        MMA(1, avB);
        BARR;
        // q2: stage B-h0(o2)
        IF_STG(so, 1, 1, 0, o2);
        BARR; LGKM0; SB0;
        RDA4(avB, 1, 3); SB0;
        MMA(2, avA);
        BARR;
        // q3: stage B-h1(o2); edge
        IF_STG(so, 1, 1, 1, o2);
        BARR; LGKM0; SB0;
        MMA(3, avB); SB0;
        VM_WAIT(so);
        BARR;
    }
#undef MMA
#undef VM_WAIT
#undef LGKM0
#undef SB0
#undef BARR
#undef IF_STG
#undef STG
#undef RDB8
#undef RDA4
#undef DSR

    // epilogue: 4 passes of 64 rows through LDS (reuses the 128KB buffer)
    float* sC = (float*)smem;
    const int q4 = lane >> 4;
    const int lr = tid >> 3;            // 0..63
    const int c0 = (tid & 7) * 4;       // scattered 16B chunks
    const long long Nll = N;
    #pragma unroll
    for (int p = 0; p < 4; p++) {
        __syncthreads();
        if (wm == (p >> 1)) {
            #pragma unroll
            for (int i = 0; i < 4; i++) {
                const int fi = (p & 1) * 4 + i;
                #pragma unroll
                for (int r = 0; r < 4; r++) {
                    const int row = i * 16 + q4 * 4 + r;
                    #pragma unroll
                    for (int j = 0; j < 4; j++)
                        sC[row * 260 + wn * 64 + j * 16 + fr] = acc[fi][j][r];
                }
            }
        }
        __syncthreads();
        const long long grow = m0 + p * 64 + lr;
        const long long gb = grow * Nll + n0;
        const float* srow = sC + lr * 260;
        #pragma unroll
        for (int g = 0; g < 8; g++) {
            const int col = c0 + g * 32;
            f32x4 v = *(const f32x4*)(srow + col);
            float vv[4] = {v[0], v[1], v[2], v[3]};
            if (bon) {
                bf16x4 bb = *(const bf16x4*)(biasz + n0 + col);
                #pragma unroll
                for (int j = 0; j < 4; j++) vv[j] = vv[j] * scale + (float)bb[j];
            } else {
                #pragma unroll
                for (int j = 0; j < 4; j++) vv[j] *= scale;
            }
            if constexpr (ACT == 1) {
                #pragma unroll
                for (int j = 0; j < 4; j++) vv[j] = gelu_fast(vv[j]);
            }
            if (ron) {
                bf16x4 rr = *(const bf16x4*)(res + gb + col);
                #pragma unroll
                for (int j = 0; j < 4; j++) vv[j] += (float)rr[j];
            }
            if constexpr (OUT_F32) {
                f32x4 o4 = {vv[0], vv[1], vv[2], vv[3]};
                *(f32x4*)((float*)Cb + coff + gb + col) = o4;
            } else {
                bf16x4 o4;
                #pragma unroll
                for (int j = 0; j < 4; j++) o4[j] = (bf16)vv[j];
                *(bf16x4*)((bf16*)Cb + coff + gb + col) = o4;
            }
        }
    }
}

// --- GEMM 128x128 double-buffered, 2 blocks/CU (r16 verbatim) ---------------
// Used for QKV (1536 blocks = 3 exact rounds) and scores/PV/Wd (512 = 1).
template<int ACT, int HAS_BIAS, int HAS_RES, int OUT_F32, int SPLITK>
__global__ __launch_bounds__(512, 4)
void gemm128d(const bf16* __restrict__ A, const bf16* __restrict__ Bt,
              const bf16* __restrict__ bias, const bf16* __restrict__ res,
              void* __restrict__ Cout, void* __restrict__ Cout2,
              int M, int N, int K, int ldk, float scale,
              long long bsA, long long bsB, long long bsC, long long bsBias)
{
    __shared__ __align__(16) char smem[65536];

    const int tid  = threadIdx.x;
    const int lane = tid & 63;
    const int wave = tid >> 6;          // 0..7
    const int wm   = wave >> 2;         // 0..1  (m half: 64 rows)
    const int wn   = wave & 3;          // 0..3  (n quarter: 32 cols)

    // bijective XCD swizzle on flat workgroup id (m204 variant)
    const int gx  = N >> 7;
    const int nwg = gx * (M >> 7);
    int wg = blockIdx.x;
    {
        const int q = nwg >> 3, r = nwg & 7;
        const int xcd = wg & 7, lid = wg >> 3;
        wg = (xcd < r ? xcd * (q + 1) : r * (q + 1) + (xcd - r) * q) + lid;
    }
    const int bx = wg % gx, by = wg / gx;
    const int m0 = by << 7, n0 = bx << 7;
    const int zi = blockIdx.y;          // batch (SPLITK=0) or k-chunk (=1)

    const bf16* Ab = A  + (SPLITK ? (long long)zi * K : (long long)zi * bsA);
    const bf16* Bb = Bt + (SPLITK ? (long long)zi * K : (long long)zi * bsB);
    const bool  bon = HAS_BIAS && (!SPLITK || zi == 0);
    const bool  ron = HAS_RES  && (!SPLITK || zi == 0);
    const bf16* biasz = HAS_BIAS ? (bias + (SPLITK ? 0 : (long long)zi * bsBias)) : nullptr;
    const long long coff = SPLITK ? 0 : (long long)zi * bsC;
    char* const Cb = (char*)((SPLITK && zi) ? Cout2 : Cout);

    // DMA sources: rows rg0, rg0+8 of the 128-row tile, granule col cg0
    // (inverse of LDS granule permutation; full 128B lines per row).
    const int rg0 = wave * 16 + (lane >> 3);
    const int cg0 = (lane & 7) ^ (lane >> 3);
    const bf16* aSrc = Ab + (long long)(m0 + rg0) * ldk + cg0 * 8;
    const bf16* bSrc = Bb + (long long)(n0 + rg0) * ldk + cg0 * 8;
    const int sq8 = 8 * ldk;

    // ds_read base addrs [buf][kk]; frag offsets via imm (mi|ni * 2048).
    const int fr = lane & 15, chk = lane >> 4;
    unsigned aAd[2][2], bAd[2][2];
    {
        const unsigned sm3 = (unsigned)(size_t)(__attribute__((address_space(3))) char*)smem;
        #pragma unroll
        for (int p = 0; p < 2; p++)
            #pragma unroll
            for (int kk = 0; kk < 2; kk++) {
                const unsigned slot = (unsigned)(((kk * 4 + chk) ^ (fr & 7)) * 16);
                aAd[p][kk] = sm3 + p * 32768 + (wm * 64 + fr) * 128 + slot;
                bAd[p][kk] = sm3 + p * 32768 + 16384 + (wn * 32 + fr) * 128 + slot;
            }
    }

#define DSR(d, b, imm) \
    asm volatile("ds_read_b128 %0, %1 offset:%c2" : "=v"(d) : "v"(b), "i"(imm))
#define MM8(mh) do { \
    _Pragma("unroll") \
    for (int _n = 0; _n < 2; _n++) { \
        acc[(mh) * 2 + 0][_n] = __builtin_amdgcn_mfma_f32_16x16x32_bf16(av[((mh) * 2 + 0) * 2 + 0], bv[_n * 2 + 0], acc[(mh) * 2 + 0][_n], 0, 0, 0); \
        acc[(mh) * 2 + 1][_n] = __builtin_amdgcn_mfma_f32_16x16x32_bf16(av[((mh) * 2 + 1) * 2 + 0], bv[_n * 2 + 0], acc[(mh) * 2 + 1][_n], 0, 0, 0); \
    } \
    _Pragma("unroll") \
    for (int _n = 0; _n < 2; _n++) { \
        acc[(mh) * 2 + 0][_n] = __builtin_amdgcn_mfma_f32_16x16x32_bf16(av[((mh) * 2 + 0) * 2 + 1], bv[_n * 2 + 1], acc[(mh) * 2 + 0][_n], 0, 0, 0); \
        acc[(mh) * 2 + 1][_n] = __builtin_amdgcn_mfma_f32_16x16x32_bf16(av[((mh) * 2 + 1) * 2 + 1], bv[_n * 2 + 1], acc[(mh) * 2 + 1][_n], 0, 0, 0); \
    } \
} while (0)
// One K-tile from buf p; stage next tile into buf p^1 when SC.
#define TILE(p, SC) do { \
    DSR(bv[0], bAd[p][0], 0);    DSR(bv[1], bAd[p][1], 0); \
    DSR(bv[2], bAd[p][0], 2048); DSR(bv[3], bAd[p][1], 2048); \
    DSR(av[0], aAd[p][0], 0);    DSR(av[1], aAd[p][1], 0); \
    DSR(av[2], aAd[p][0], 2048); DSR(av[3], aAd[p][1], 2048); \
    DSR(av[4], aAd[p][0], 4096); DSR(av[5], aAd[p][1], 4096); \
    DSR(av[6], aAd[p][0], 6144); DSR(av[7], aAd[p][1], 6144); \
    if (SC) { \
        bf16* _dA = (bf16*)(smem + ((p) ^ 1) * 32768 + wave * 2048); \
        bf16* _dB = (bf16*)(smem + ((p) ^ 1) * 32768 + 16384 + wave * 2048); \
        async_cp16(aSrc, _dA);       async_cp16(aSrc + sq8, _dA + 512); \
        async_cp16(bSrc, _dB);       async_cp16(bSrc + sq8, _dB + 512); \
        aSrc += 64; bSrc += 64; \
    } \
    asm volatile("s_waitcnt lgkmcnt(4)"); \
    __builtin_amdgcn_sched_barrier(0); \
    __builtin_amdgcn_s_setprio(1); \
    MM8(0); \
    __builtin_amdgcn_s_setprio(0); \
    asm volatile("s_waitcnt lgkmcnt(0)"); \
    __builtin_amdgcn_sched_barrier(0); \
    __builtin_amdgcn_s_setprio(1); \
    MM8(1); \
    __builtin_amdgcn_s_setprio(0); \
    __builtin_amdgcn_sched_barrier(0); \
    asm volatile("s_waitcnt vmcnt(0)"); \
    __builtin_amdgcn_s_barrier(); \
} while (0)

    const int NT = K >> 6, NH = NT >> 1;

    // prologue: stage tile 0 into buf0; sources then point at tile 1
    {
        bf16* dA = (bf16*)(smem + wave * 2048);
        bf16* dB = (bf16*)(smem + 16384 + wave * 2048);
        async_cp16(aSrc, dA);       async_cp16(aSrc + sq8, dA + 512);
        async_cp16(bSrc, dB);       async_cp16(bSrc + sq8, dB + 512);
        aSrc += 64; bSrc += 64;
    }

    f32x4 acc[4][2];
    {
        const f32x4 zf = {0.f, 0.f, 0.f, 0.f};
        #pragma unroll
        for (int i = 0; i < 4; i++) {
            acc[i][0] = zf; acc[i][1] = zf;
        }
    }
    bf16x8 av[8], bv[4];

    asm volatile("s_waitcnt vmcnt(0)");
    __builtin_amdgcn_s_barrier();

    for (int it = 0; it < NH; ++it) {
        const bool so = (it + 1 < NH);
        TILE(0, true);     // tile 2it   (buf0); stage 2it+1 -> buf1
        TILE(1, so);       // tile 2it+1 (buf1); stage 2it+2 -> buf0
    }
#undef TILE
#undef MM8
#undef DSR

    // epilogue: 2 passes of 64 rows through LDS
    float* sC = (float*)smem;
    const int q4 = lane >> 4;
    const int lr = tid >> 3;            // 0..63
    const int c0 = (tid & 7) * 4;
    const long long Nll = N;
    #pragma unroll
    for (int p2 = 0; p2 < 2; p2++) {
        __syncthreads();
        if (wm == p2) {
            #pragma unroll
            for (int mi = 0; mi < 4; mi++)
                #pragma unroll
                for (int r = 0; r < 4; r++) {
                    const int row = mi * 16 + q4 * 4 + r;
                    #pragma unroll
                    for (int ni = 0; ni < 2; ni++)
                        sC[row * 132 + wn * 32 + ni * 16 + fr] = acc[mi][ni][r];
                }
        }
        __syncthreads();
        const long long grow = m0 + p2 * 64 + lr;
        const long long gb = grow * Nll + n0;
        const float* srow = sC + lr * 132;
        #pragma unroll
        for (int g = 0; g < 4; g++) {
            const int col = c0 + g * 32;
            f32x4 v = *(const f32x4*)(srow + col);
            float vv[4] = {v[0], v[1], v[2], v[3]};
            if (bon) {
                bf16x4 bb = *(const bf16x4*)(biasz + n0 + col);
                #pragma unroll
                for (int j = 0; j < 4; j++) vv[j] = vv[j] * scale + (float)bb[j];
            } else {
                #pragma unroll
                for (int j = 0; j < 4; j++) vv[j] *= scale;
            }
            if constexpr (ACT == 1) {
                #pragma unroll
                for (int j = 0; j < 4; j++) vv[j] = gelu_fast(vv[j]);
            }
            if (ron) {
                bf16x4 rr = *(const bf16x4*)(res + gb + col);
                #pragma unroll
                for (int j = 0; j < 4; j++) vv[j] += (float)rr[j];
            }
            if constexpr (OUT_F32) {
                f32x4 o4 = {vv[0], vv[1], vv[2], vv[3]};
                *(f32x4*)((float*)Cb + coff + gb + col) = o4;
            } else {
                bf16x4 o4;
                #pragma unroll
                for (int j = 0; j < 4; j++) o4[j] = (bf16)vv[j];
                *(bf16x4*)((bf16*)Cb + coff + gb + col) = o4;
            }
        }
    }
}

// --- softmax / layernorm ----------------------------------------------------

__global__ __launch_bounds__(256)
void softmax_inplace(bf16* __restrict__ P, int N)
{
    const long long row = blockIdx.x;
    bf16* p = P + row * (long long)N;
    const int t = threadIdx.x;
    bf16x4 xin = *(const bf16x4*)(p + t * 4);
    float xs[4];
    #pragma unroll
    for (int i = 0; i < 4; i++) xs[i] = (float)xin[i];

    float m = fmaxf(fmaxf(xs[0], xs[1]), fmaxf(xs[2], xs[3]));
    #pragma unroll
    for (int off = 32; off > 0; off >>= 1) m = fmaxf(m, __shfl_xor(m, off, 64));
    __shared__ float red[4];
    if ((t & 63) == 0) red[t >> 6] = m;
    __syncthreads();
    m = fmaxf(fmaxf(red[0], red[1]), fmaxf(red[2], red[3]));

    float e[4], s = 0.f;
    #pragma unroll
    for (int i = 0; i < 4; i++) { e[i] = __expf(xs[i] - m); s += e[i]; }
    #pragma unroll
    for (int off = 32; off > 0; off >>= 1) s += __shfl_xor(s, off, 64);
    __shared__ float red2[4];
    if ((t & 63) == 0) red2[t >> 6] = s;
    __syncthreads();
    s = red2[0] + red2[1] + red2[2] + red2[3];
    const float inv = 1.f / s;

    bf16x4 o;
    #pragma unroll
    for (int i = 0; i < 4; i++) o[i] = (bf16)(e[i] * inv);
    *(bf16x4*)(p + t * 4) = o;
}

// IN_MODE: 0 = bf16, 1 = f32, 2 = f32+f32 (split-K), 3 = bf16+bf16 (split-K)
template<int IN_MODE, int OUT_F32>
__global__ __launch_bounds__(256)
void layernorm_rows(const void* __restrict__ Z, const void* __restrict__ Z2,
                    const bf16* __restrict__ g, const bf16* __restrict__ b,
                    void* __restrict__ outp, int N)
{
    const long long row = blockIdx.x;
    const int t = threadIdx.x;
    float xv[4];
    if constexpr (IN_MODE == 1 || IN_MODE == 2) {
        f32x4 zin = *(const f32x4*)((const float*)Z + row * (long long)N + t * 4);
        #pragma unroll
        for (int i = 0; i < 4; i++) xv[i] = zin[i];
        if constexpr (IN_MODE == 2) {
            f32x4 z2 = *(const f32x4*)((const float*)Z2 + row * (long long)N + t * 4);
            #pragma unroll
            for (int i = 0; i < 4; i++) xv[i] += z2[i];
        }
    } else {
        bf16x4 zin = *(const bf16x4*)((const bf16*)Z + row * (long long)N + t * 4);
        #pragma unroll
        for (int i = 0; i < 4; i++) xv[i] = (float)zin[i];
        if constexpr (IN_MODE == 3) {
            bf16x4 z2 = *(const bf16x4*)((const bf16*)Z2 + row * (long long)N + t * 4);
            #pragma unroll
            for (int i = 0; i < 4; i++) xv[i] += (float)z2[i];
        }
    }

    float s = xv[0] + xv[1] + xv[2] + xv[3];
    #pragma unroll
    for (int off = 32; off > 0; off >>= 1) s += __shfl_xor(s, off, 64);
    __shared__ float r1[4];
    if ((t & 63) == 0) r1[t >> 6] = s;
    __syncthreads();
    const float mu = (r1[0] + r1[1] + r1[2] + r1[3]) * (1.f / 1024.f);

    float d[4];
    float sq = 0.f;
    #pragma unroll
    for (int i = 0; i < 4; i++) { d[i] = xv[i] - mu; sq += d[i] * d[i]; }
    #pragma unroll
    for (int off = 32; off > 0; off >>= 1) sq += __shfl_xor(sq, off, 64);
    __shared__ float r2[4];
    if ((t & 63) == 0) r2[t >> 6] = sq;
    __syncthreads();
    const float var = (r2[0] + r2[1] + r2[2] + r2[3]) * (1.f / 1024.f);
    const float rstd = rsqrtf(var + 1e-12f);

    bf16x4 gv = *(const bf16x4*)(g + t * 4);
    bf16x4 bv = *(const bf16x4*)(b + t * 4);
    if constexpr (OUT_F32) {
        f32x4 o;
        #pragma unroll
        for (int i = 0; i < 4; i++)
            o[i] = d[i] * rstd * (float)gv[i] + (float)bv[i];
        *(f32x4*)((float*)outp + row * (long long)N + t * 4) = o;
    } else {
        bf16x4 o;
        #pragma unroll
        for (int i = 0; i < 4; i++)
            o[i] = (bf16)(d[i] * rstd * (float)gv[i] + (float)bv[i]);
        *(bf16x4*)((bf16*)outp + row * (long long)N + t * 4) = o;
    }
}

// --- driver -----------------------------------------------------------------

extern "C" void kernel_launch(void* const* d_in, const int* in_sizes, int n_in,
                              void* d_out, int out_size, void* d_ws, size_t ws_size,
                              hipStream_t stream)
{
    (void)in_sizes; (void)n_in; (void)out_size;

    const void* x  = d_in[0];
    const void* Wq = d_in[1];  const void* bq = d_in[2];
    const void* Wk = d_in[3];  const void* bk = d_in[4];
    const void* Wv = d_in[5];  const void* bv = d_in[6];
    const void* Wd = d_in[7];  const void* bd = d_in[8];
    const void* g1 = d_in[9];  const void* b1 = d_in[10];
    const void* Wi = d_in[11]; const void* bi = d_in[12];
    const void* Wo = d_in[13]; const void* bo = d_in[14];
    const void* g2 = d_in[15]; const void* b2 = d_in[16];

    const int Bb = 8, S = 1024, E = 1024, F = 4096;
    const int M = Bb * S;                         // 8192
    const long long SE = (long long)S * E, SS = (long long)S * S;
    const long long ME = (long long)M * E;

    char* ws = (char*)d_ws;
    const size_t MB = 1024ull * 1024ull;
    int*  dflag = (int*)(ws + 0);
    bf16* small = (bf16*)(ws + 64 * 1024);
    bf16* bq_c = small + 0 * 1024;                 // bq,bk,bv contiguous
    bf16* bd_c = small + 3 * 1024;
    bf16* g1_c = small + 4 * 1024;
    bf16* b1_c = small + 5 * 1024;
    bf16* g2_c = small + 6 * 1024;
    bf16* b2_c = small + 7 * 1024;
    bf16* bo_c = small + 8 * 1024;
    bf16* bi_c = small + 9216;
    bf16* WoT  = (bf16*)(ws + 1 * MB);    // [E,F] 8MB, live to z2
    bf16* WiT  = (bf16*)(ws + 9 * MB);    // [F,E] 8MB, live to ff
    bf16* WqT  = (bf16*)(ws + 17 * MB);   // Wq/Wk/Wv/Wd contiguous [4][E][E]
    bf16* WkT  = (bf16*)(ws + 19 * MB);
    bf16* WvT  = (bf16*)(ws + 21 * MB);
    bf16* WdT  = (bf16*)(ws + 23 * MB);
    bf16* xb   = (bf16*)(ws + 25 * MB);   // [M,E] 16MB, live to z1
    float* out = (float*)d_out;

    diag_init<<<1, 64, 0, stream>>>(x, dflag);

    if (ws_size < 70 * MB) { sentinel_small<<<1, 1, 0, stream>>>(out); return; }

    SmallPtrs sp;
    sp.p[0] = bq; sp.p[1] = bk; sp.p[2] = bv; sp.p[3] = bd; sp.p[4] = g1;
    sp.p[5] = b1; sp.p[6] = g2; sp.p[7] = b2; sp.p[8] = bo; sp.p[9] = bi;
    convert_small<<<52, 256, 0, stream>>>(sp, small, dflag);
    convert_vec4<<<8192, 256, 0, stream>>>(x, xb, ME / 4, dflag);

    const dim3 tb(32, 8, 1);
    W4Ptrs wp; wp.p[0] = Wq; wp.p[1] = Wk; wp.p[2] = Wv; wp.p[3] = Wd;
    transpose_quad<<<dim3(E/32, E/32, 4), tb, 0, stream>>>(wp, WqT, E, E, dflag);
    transpose_dual<<<dim3(F/32, E/32), tb, 0, stream>>>(Wi, WiT, E, F, dflag);
    transpose_dual<<<dim3(E/32, F/32), tb, 0, stream>>>(Wo, WoT, F, E, dflag);

    if (ws_size >= 121 * MB) {
        // ---- batched path ----
        bf16* qkv  = (bf16*)(ws + 41 * MB);   // [3][M,E] 48MB contiguous
        bf16* q    = qkv;
        bf16* k    = qkv + ME;
        bf16* v    = qkv + 2 * ME;
        bf16* vT   = (bf16*)(ws + 89 * MB);   // [B,E,S] 16MB
        bf16* P    = (bf16*)(ws + 73 * MB);   // over v (dead after vT)
        bf16* attn = (bf16*)(ws + 41 * MB);   // over q (dead after scores)
        bf16* z1   = (bf16*)(ws + 57 * MB);   // over k (dead after scores)
        bf16* h1   = (bf16*)(ws + 41 * MB);   // over attn (dead after z1)
        bf16* ff   = (bf16*)(ws + 57 * MB);   // 64MB, spans 57..121 (z1/P/vT dead)
        bf16* z2a  = (bf16*)(ws + 9 * MB);    // 16MB over WiT (dead after FF)
        bf16* z2b  = (bf16*)(ws + 25 * MB);   // 16MB over xb (dead after Wd)

        // QKV: 128^2 (1536 blocks @ 2/CU = 3 exact rounds), z=3 weights
        gemm128d<0,1,0,0,0><<<dim3((E/128)*(M/128), 3), 512, 0, stream>>>(
            xb, WqT, bq_c, nullptr, qkv, nullptr, M, E, E, E, 1.f,
            0, (long long)E * E, ME, E);
        transpose_b<<<dim3(E/32, S/32, Bb), tb, 0, stream>>>(v, vT, S, E);
        // scores: 128^2, z=8 batches
        gemm128d<0,0,0,0,0><<<dim3((S/128)*(S/128), Bb), 512, 0, stream>>>(
            q, k, nullptr, nullptr, P, nullptr, S, S, E, E, 0.03125f,
            SE, SE, SS, 0);
        softmax_inplace<<<M, 256, 0, stream>>>(P, S);
        // PV: 128^2, z=8 batches
        gemm128d<0,0,0,0,0><<<dim3((E/128)*(S/128), Bb), 512, 0, stream>>>(
            P, vT, nullptr, nullptr, attn, nullptr, S, E, S, S, 1.f,
            SS, SE, SE, 0);
        // Wd + residual: 128^2
        gemm128d<0,1,1,0,0><<<dim3((E/128)*(M/128), 1), 512, 0, stream>>>(
            attn, WdT, bd_c, xb, z1, nullptr, M, E, E, E, 1.f, 0, 0, 0, 0);
        layernorm_rows<0,0><<<M, 256, 0, stream>>>(z1, nullptr, g1_c, b1_c, h1, E);
        // FF: 256^2 (512 blocks = 2 exact rounds), gelu fused
        gemm256<1,1,0,0,0><<<dim3((F/256)*(M/256), 1), 512, 0, stream>>>(
            h1, WiT, bi_c, nullptr, ff, nullptr, M, F, E, E, 1.f, 0, 0, 0);
        // Wo: 256^2 split-K=2 (256 blocks = 1 exact round); bf16 partials at
        // race-free offsets (z2a over dead WiT, z2b over dead xb).
        gemm256<0,1,1,0,1><<<dim3((E/256)*(M/256), 2), 512, 0, stream>>>(
            ff, WoT, bo_c, h1, z2a, z2b, M, E, F / 2, F, 1.f, 0, 0, 0);
        layernorm_rows<3,1><<<M, 256, 0, stream>>>(z2a, z2b, g2_c, b2_c, out, E);
    } else {
        // ---- fallback: per-batch (peak 67MB), z2 in bf16 ----
        bf16* qkv_b = (bf16*)(ws + 41 * MB);  // [3][S,E] 6MB contiguous
        bf16* q_b   = qkv_b;
        bf16* k_b   = qkv_b + SE;
        bf16* v_b   = qkv_b + 2 * SE;
        bf16* vT_b  = (bf16*)(ws + 47 * MB);
        bf16* P_b   = (bf16*)(ws + 49 * MB);
        bf16* at_b  = (bf16*)(ws + 51 * MB);
        bf16* z1_b  = (bf16*)(ws + 53 * MB);
        bf16* h1_b  = (bf16*)(ws + 55 * MB);
        bf16* ff_b  = (bf16*)(ws + 57 * MB);  // 8MB
        bf16* z2_b  = (bf16*)(ws + 65 * MB);  // 2MB

        for (int b = 0; b < Bb; b++) {
            const bf16* x_b = xb + (long long)b * SE;
            gemm_bt<0,1,0,0><<<dim3(8, 8, 3), 512, 0, stream>>>(
                x_b, WqT, bq_c, nullptr, qkv_b, S, E, E, 1.f, 0, (long long)E * E, SE, E);
            transpose_b<<<dim3(E/32, S/32), tb, 0, stream>>>(v_b, vT_b, S, E);
            gemm_bt<0,0,0,0><<<dim3(8, 8), 512, 0, stream>>>(
                q_b, k_b, nullptr, nullptr, P_b, S, S, E, 0.03125f, 0, 0, 0, 0);
            softmax_inplace<<<S, 256, 0, stream>>>(P_b, S);
            gemm_bt<0,0,0,0><<<dim3(8, 8), 512, 0, stream>>>(
                P_b, vT_b, nullptr, nullptr, at_b, S, E, S, 1.f, 0, 0, 0, 0);
            gemm_bt<0,1,1,0><<<dim3(8, 8), 512, 0, stream>>>(
                at_b, WdT, bd_c, x_b, z1_b, S, E, E, 1.f, 0, 0, 0, 0);
            layernorm_rows<0,0><<<S, 256, 0, stream>>>(z1_b, nullptr, g1_c, b1_c, h1_b, E);
            gemm_bt<1,1,0,0><<<dim3(32, 8), 512, 0, stream>>>(
                h1_b, WiT, bi_c, nullptr, ff_b, S, F, E, 1.f, 0, 0, 0, 0);
            gemm_bt<0,1,1,0><<<dim3(8, 8), 512, 0, stream>>>(
                ff_b, WoT, bo_c, h1_b, z2_b, S, E, F, 1.f, 0, 0, 0, 0);
            layernorm_rows<0,1><<<S, 256, 0, stream>>>(z2_b, nullptr, g2_c, b2_c, out + (long long)b * SE, E);
        }
    }
}